// Round 9
// baseline (473.849 us; speedup 1.0000x reference)
//
#include <hip/hip_runtime.h>
#include <stdint.h>

#define DEV __device__ __forceinline__

typedef __attribute__((ext_vector_type(8))) short bf16x8;
typedef __attribute__((ext_vector_type(4))) float f32x4;
typedef __attribute__((ext_vector_type(16))) float f32x16;

DEV unsigned short f2bf(float f) {
  union { float f; uint32_t u; } v; v.f = f;
  uint32_t r = v.u + 0x7fffu + ((v.u >> 16) & 1u);
  return (unsigned short)(r >> 16);
}

DEV void lds_load16(void* dst, const void* src) {
  __builtin_amdgcn_global_load_lds(
      (const __attribute__((address_space(1))) unsigned int*)src,
      (__attribute__((address_space(3))) unsigned int*)dst, 16, 0, 0);
}

// ---------------- prep kernels ----------------

__global__ void conv_x_k(const float* __restrict__ x, unsigned short* __restrict__ o) {
  const int i = blockIdx.x * 256 + threadIdx.x;  // 1572864 float4s
  const float4 v = ((const float4*)x)[i];
  ushort4 u;
  u.x = f2bf(v.x); u.y = f2bf(v.y); u.z = f2bf(v.z); u.w = f2bf(v.w);
  ((ushort4*)o)[i] = u;
}

// E (int32) -> lane-ordered masked-index records.
__global__ void conv_E_k(const int* __restrict__ E, const int* __restrict__ Mm,
                         uint8_t* __restrict__ E8L) {
  const int tid = blockIdx.x * 256 + threadIdx.x;  // 2097152
  const int k4 = tid & 255;
  const int q = (tid >> 8) & 1023;
  const int b = tid >> 18;
  const uint4 e = ((const uint4*)E)[tid];
  const int mq = Mm[b * 1024 + q];
  const int4 mk = *(const int4*)&Mm[b * 1024 + k4 * 4];
  uint32_t r;
  {
    const uint32_t b0 = (mq && mk.x) ? (e.x & 31u) : 32u;
    const uint32_t b1 = (mq && mk.y) ? (e.y & 31u) : 32u;
    const uint32_t b2 = (mq && mk.z) ? (e.z & 31u) : 32u;
    const uint32_t b3 = (mq && mk.w) ? (e.w & 31u) : 32u;
    r = b0 | (b1 << 8) | (b2 << 16) | (b3 << 24);
  }
  const int kt = k4 >> 4;
  const int k4t = k4 & 15;
  const int h = k4t & 1, c = (k4t >> 1) & 3, a = k4t >> 3;
  const int lane = (h << 5) | (q & 31);
  const int qw = q >> 5;
  const int j = a * 4 + c;
  const size_t rec = ((((size_t)b * 32 + qw) * 16 + kt) * 64 + lane) * 32 + j * 4;
  *(uint32_t*)(E8L + rec) = r;
}

// Wt[c][k] = W[k][c], bf16 pack. grid (12,12,4)
__global__ void transp_w_k(const float* __restrict__ Wq, const float* __restrict__ Wk,
                           const float* __restrict__ Wv, const float* __restrict__ Wo,
                           unsigned short* __restrict__ wtqkv, unsigned short* __restrict__ wot) {
  __shared__ float tile[64][65];
  const int z = blockIdx.z;
  const float* W = (z == 0) ? Wq : (z == 1) ? Wk : (z == 2) ? Wv : Wo;
  unsigned short* D = (z < 3) ? wtqkv + (size_t)z * 768 * 768 : wot;
  const int k0 = blockIdx.x * 64;
  const int c0 = blockIdx.y * 64;
  const int t = threadIdx.x;
#pragma unroll
  for (int i = 0; i < 4; ++i) {
    const int idx = i * 256 + t;
    const int r = idx >> 4;
    const int cq = (idx & 15) * 4;
    const float4 v = *(const float4*)&W[(k0 + r) * 768 + c0 + cq];
    tile[r][cq] = v.x; tile[r][cq + 1] = v.y; tile[r][cq + 2] = v.z; tile[r][cq + 3] = v.w;
  }
  __syncthreads();
#pragma unroll
  for (int i = 0; i < 4; ++i) {
    const int idx = i * 256 + t;
    const int c = idx >> 4;
    const int kq = (idx & 15) * 4;
    ushort4 u;
    u.x = f2bf(tile[kq][c]);     u.y = f2bf(tile[kq + 1][c]);
    u.z = f2bf(tile[kq + 2][c]); u.w = f2bf(tile[kq + 3][c]);
    *(ushort4*)&D[(c0 + c) * 768 + k0 + kq] = u;
  }
}

// ---------------- QKV GEMM: 256x256 tile, reg-staged, 8 waves ----------------
// A (8192,768) bf16; Bt = wtqkv (2304,768). Grid (32,9), block 512.
// Staging: global_load_dwordx4 -> regs (1 iter lead) -> ds_write_b128.
// One __syncthreads per K-step. Double-buffered 64 KB LDS.
// launch_bounds (512,4) => 2 blocks/CU co-resident: all 288 blocks resident,
// 2-deep block-level latency overlap per CU.
__global__ __launch_bounds__(512, 4)
void gemm256_qkv(const unsigned short* __restrict__ A, const unsigned short* __restrict__ Bt,
                 const float* __restrict__ b0, const float* __restrict__ b1,
                 const float* __restrict__ b2,
                 unsigned short* __restrict__ Qb, unsigned short* __restrict__ Kb,
                 unsigned short* __restrict__ Vt) {
  __shared__ __attribute__((aligned(16))) unsigned short lds[2][16384];  // [buf][A 8192 | B 8192]
  const int t = threadIdx.x;
  const int lane = t & 63;
  const int wid = t >> 6;        // 0..7
  const int wm2 = wid >> 2;      // 0..1 : 128-row band
  const int wn2 = wid & 3;       // 0..3 : 64-col band
  const int g = lane >> 4;
  const int c15 = lane & 15;

  const int m0 = blockIdx.x * 256;
  const int n0 = blockIdx.y * 256;

  const f32x4 Z4 = {0.f, 0.f, 0.f, 0.f};
  f32x4 acc[8][4];
#pragma unroll
  for (int m = 0; m < 8; ++m)
#pragma unroll
    for (int n = 0; n < 4; ++n) acc[m][n] = Z4;

  // staging geometry: thread loads row srow, k-chunks skc and skc+2 (8 elems each)
  const int srow = t & 255;
  const int skc = t >> 8;                       // 0 or 1
  const unsigned short* gA = A + (size_t)(m0 + srow) * 768 + skc * 8;
  const unsigned short* gB = Bt + (size_t)(n0 + srow) * 768 + skc * 8;
  const int u0e = (skc * 256 + srow) * 8;       // LDS elem: [kc][row] slots

  bf16x8 pA0, pA1, pB0, pB1;
  auto gload = [&](int kt) {
    const unsigned short* a = gA + kt * 32;
    const unsigned short* b = gB + kt * 32;
    pA0 = *(const bf16x8*)a;
    pA1 = *(const bf16x8*)(a + 16);   // k-chunk skc+2
    pB0 = *(const bf16x8*)b;
    pB1 = *(const bf16x8*)(b + 16);
  };
  auto swrite = [&](int buf) {
    *(bf16x8*)&lds[buf][u0e] = pA0;
    *(bf16x8*)&lds[buf][u0e + 4096] = pA1;
    *(bf16x8*)&lds[buf][8192 + u0e] = pB0;
    *(bf16x8*)&lds[buf][8192 + u0e + 4096] = pB1;
  };

  gload(0);
  swrite(0);           // tile 0 -> buf 0 (ds_write waits on its own loads)
  gload(1);            // tile 1 in regs, in flight during first compute
  __syncthreads();

  int cur = 0;
  for (int kt = 0; kt < 24; ++kt) {
    bf16x8 av[8], bvv[4];
#pragma unroll
    for (int m = 0; m < 8; ++m)
      av[m] = *(const bf16x8*)&lds[cur][g * 2048 + (wm2 * 128 + m * 16 + c15) * 8];
#pragma unroll
    for (int n = 0; n < 4; ++n)
      bvv[n] = *(const bf16x8*)&lds[cur][8192 + g * 2048 + (wn2 * 64 + n * 16 + c15) * 8];
#pragma unroll
    for (int m = 0; m < 8; ++m)
#pragma unroll
      for (int n = 0; n < 4; ++n)
        acc[m][n] = __builtin_amdgcn_mfma_f32_16x16x32_bf16(av[m], bvv[n], acc[m][n], 0, 0, 0);
    if (kt + 1 < 24) {
      swrite(cur ^ 1);               // write tile kt+1 (regs) to other buffer
      if (kt + 2 < 24) gload(kt + 2);  // issue loads for tile kt+2
    }
    __syncthreads();                 // reads of buf[cur] + writes of buf[cur^1] done
    cur ^= 1;
  }

  // epilogue: this wave's 64 cols = exactly one head of one of Q/K/V
  const int cwb = n0 + wn2 * 64;     // 64-aligned within one 768-mat
  const int mat = cwb / 768;
  const int cwm = cwb - mat * 768;
  const int hh = cwm >> 6;
  const float* bsel = (mat == 0) ? b0 : (mat == 1) ? b1 : b2;
  unsigned short* qk = (mat == 0) ? Qb : Kb;
#pragma unroll
  for (int n = 0; n < 4; ++n) {
    const int dd = n * 16 + c15;
    const float bval = bsel[hh * 64 + dd];
#pragma unroll
    for (int m = 0; m < 8; ++m) {
      const int r0 = m0 + wm2 * 128 + m * 16 + g * 4;
      const int bb = r0 >> 10;
      const int nn = r0 & 1023;
      if (mat < 2) {
        unsigned short* dst = qk + ((bb * 12 + hh) * 1024 + nn) * 64 + dd;
#pragma unroll
        for (int r = 0; r < 4; ++r) dst[r * 64] = f2bf(acc[m][n][r] + bval);
      } else {
        ushort4 w;
        w.x = f2bf(acc[m][n][0] + bval);
        w.y = f2bf(acc[m][n][1] + bval);
        w.z = f2bf(acc[m][n][2] + bval);
        w.w = f2bf(acc[m][n][3] + bval);
        *(ushort4*)&Vt[((bb * 12 + hh) * 64 + dd) * 1024 + nn] = w;
      }
    }
  }
}

// ---------------- output GEMM: 128x128, BK=32, 2D grid, 4 blocks/CU ----------------
__global__ __launch_bounds__(256, 4)
void gemm_out(const unsigned short* __restrict__ A, const unsigned short* __restrict__ Bt,
              const float* __restrict__ b0, float* __restrict__ Fo) {
  __shared__ __attribute__((aligned(16))) unsigned short lds[2][8192];
  const int t = threadIdx.x;
  const int lane = t & 63;
  const int wid = t >> 6;
  const int m0 = blockIdx.x * 128;
  const int n0 = blockIdx.y * 128;
  const int wm = (wid >> 1) * 64;
  const int wn = (wid & 1) * 64;
  const int srow = t & 127;
  const int sk8 = (t >> 7) * 8;

  const unsigned short* gA = A + (m0 + srow) * 768 + sk8;
  const unsigned short* gB = Bt + (n0 + srow) * 768 + sk8;

  const f32x4 Z4 = {0.f, 0.f, 0.f, 0.f};
  f32x4 acc[4][4];
#pragma unroll
  for (int m = 0; m < 4; ++m)
#pragma unroll
    for (int n = 0; n < 4; ++n) acc[m][n] = Z4;

  const int a_off = (lane >> 4) * 1024 + (wm + (lane & 15)) * 8;
  const int b_off = 4096 + (lane >> 4) * 1024 + (wn + (lane & 15)) * 8;

  auto stage = [&](int buf, int kt) {
    unsigned short* dA = &lds[buf][0] + wid * 512;
    unsigned short* dB = &lds[buf][4096] + wid * 512;
    const unsigned short* sA = gA + kt * 32;
    const unsigned short* sB = gB + kt * 32;
    lds_load16(dA, sA);
    lds_load16(dA + 2048, sA + 16);
    lds_load16(dB, sB);
    lds_load16(dB + 2048, sB + 16);
  };

  stage(0, 0);
  int cur = 0;
  for (int kt = 0; kt < 24; ++kt) {
    __syncthreads();
    if (kt + 1 < 24) stage(cur ^ 1, kt + 1);
    bf16x8 av[4], bvv[4];
#pragma unroll
    for (int m = 0; m < 4; ++m) av[m] = *(const bf16x8*)&lds[cur][a_off + m * 128];
#pragma unroll
    for (int n = 0; n < 4; ++n) bvv[n] = *(const bf16x8*)&lds[cur][b_off + n * 128];
#pragma unroll
    for (int m = 0; m < 4; ++m)
#pragma unroll
      for (int n = 0; n < 4; ++n)
        acc[m][n] = __builtin_amdgcn_mfma_f32_16x16x32_bf16(av[m], bvv[n], acc[m][n], 0, 0, 0);
    cur ^= 1;
  }

  const int g = lane >> 4;
  const int c15 = lane & 15;
#pragma unroll
  for (int n = 0; n < 4; ++n) {
    const int col = n0 + wn + n * 16 + c15;
    const float bval = b0[col];
#pragma unroll
    for (int m = 0; m < 4; ++m) {
      const int r0 = m0 + wm + m * 16 + g * 4;
#pragma unroll
      for (int r = 0; r < 4; ++r) Fo[(r0 + r) * 768 + col] = acc[m][n][r] + bval;
    }
  }
}

// ---------------- fused attention, swapped-QK^T 32x32 (m214 structure) ----------------
__global__ __launch_bounds__(256, 4)
void attn_fused(const unsigned short* __restrict__ Qb, const unsigned short* __restrict__ Kb,
                const unsigned short* __restrict__ Vt, const uint8_t* __restrict__ E8L,
                const float* __restrict__ emb, unsigned short* __restrict__ AO) {
  __shared__ __attribute__((aligned(16))) unsigned short Ks[2][4096];  // [krow64][d64] swz
  __shared__ __attribute__((aligned(16))) unsigned short Vs[2][4096];  // [d64][k64] swz
  __shared__ float ttab[33];
  __shared__ float red[4][32];

  const int t = threadIdx.x;
  const int lane = t & 63;
  const int wid = t >> 6;
  const int l31 = lane & 31;
  const int hl = lane >> 5;

  const int id = blockIdx.x;
  const int sw = (id & 7) * 96 + (id >> 3);
  const int b = sw / 96;
  const int rem = sw - b * 96;
  const int h = rem >> 3;
  const int qb = rem & 7;
  const int bh = b * 12 + h;
  const int qw = qb * 4 + wid;
  const int q0 = qw * 32;

  if (t < 33) ttab[t] = (t < 32) ? emb[t * 12 + h] * 1.44269504f : -1e30f;

  bf16x8 qf[4];
  {
    const unsigned short* qp = Qb + ((size_t)bh * 1024 + q0 + l31) * 64 + hl * 8;
#pragma unroll
    for (int dc = 0; dc < 4; ++dc) qf[dc] = *(const bf16x8*)(qp + dc * 16);
  }

  auto stageKV = [&](int buf, int kt) {
#pragma unroll
    for (int i = 0; i < 2; ++i) {
      const int c = i * 256 + t;
      const int row = c >> 3, c16 = c & 7;
      const int sc = (c16 ^ (row & 7)) * 8;
      lds_load16(&Ks[buf][i * 2048 + wid * 512],
                 Kb + ((size_t)bh * 1024 + kt * 64 + row) * 64 + sc);
      lds_load16(&Vs[buf][i * 2048 + wid * 512],
                 Vt + ((size_t)bh * 64 + row) * 1024 + kt * 64 + sc);
    }
  };

  const uint8_t* ebase = E8L + (((size_t)(b * 32 + qw)) * 16 * 64 + lane) * 32;

  stageKV(0, 0);
  uint4 e0 = *(const uint4*)(ebase);
  uint4 e1 = *(const uint4*)(ebase + 16);

  const f32x16 Z16 = {0.f};
  f32x16 oacc0 = Z16, oacc1 = Z16;
  float m = -3.0e38f, lsum = 0.f;
  int cur = 0;

  for (int kt = 0; kt < 16; ++kt) {
    __syncthreads();
    if (kt + 1 < 16) stageKV(cur ^ 1, kt + 1);
    uint4 en0 = e0, en1 = e1;  // defined on last iter
    if (kt + 1 < 16) {
      en0 = *(const uint4*)(ebase + (kt + 1) * 2048);
      en1 = *(const uint4*)(ebase + (kt + 1) * 2048 + 16);
    }

    f32x16 s0 = Z16, s1 = Z16;
    __builtin_amdgcn_s_setprio(1);
#pragma unroll
    for (int dc = 0; dc < 4; ++dc) {
      const int gch = (dc * 2 + hl);
      const bf16x8 a0 = *(const bf16x8*)((const char*)Ks[cur] +
                         l31 * 128 + ((gch ^ (l31 & 7)) << 4));
      const bf16x8 a1 = *(const bf16x8*)((const char*)Ks[cur] +
                         (32 + l31) * 128 + ((gch ^ ((32 + l31) & 7)) << 4));
      s0 = __builtin_amdgcn_mfma_f32_32x32x16_bf16(a0, qf[dc], s0, 0, 0, 0);
      s1 = __builtin_amdgcn_mfma_f32_32x32x16_bf16(a1, qf[dc], s1, 0, 0, 0);
    }
    __builtin_amdgcn_s_setprio(0);

    const uint32_t ed[8] = {e0.x, e0.y, e0.z, e0.w, e1.x, e1.y, e1.z, e1.w};
    float w0[16], w1[16];
#pragma unroll
    for (int r = 0; r < 16; ++r) {
      const uint32_t d0 = ed[r >> 2], d1 = ed[4 + (r >> 2)];
      const int sh = (r & 3) * 8;
      w0[r] = fmaf(s0[r], 0.18033688f, ttab[(d0 >> sh) & 0xffu]);
      w1[r] = fmaf(s1[r], 0.18033688f, ttab[(d1 >> sh) & 0xffu]);
    }

    float rm = fmaxf(w0[0], w1[0]);
#pragma unroll
    for (int r = 1; r < 16; ++r) rm = fmaxf(rm, fmaxf(w0[r], w1[r]));
    rm = fmaxf(rm, __shfl_xor(rm, 32, 64));

    if (__any(rm > m + 11.5415603f)) {
      const float mn = fmaxf(m, rm);
      const float scl = exp2f(m - mn);
      m = mn;
      lsum *= scl;
#pragma unroll
      for (int r = 0; r < 16; ++r) { oacc0[r] *= scl; oacc1[r] *= scl; }
    }

    float rs0 = 0.f, rs1 = 0.f, rs2 = 0.f, rs3 = 0.f;
#pragma unroll
    for (int r = 0; r < 16; ++r) {
      w0[r] = exp2f(w0[r] - m);
      w1[r] = exp2f(w1[r] - m);
    }
#pragma unroll
    for (int r = 0; r < 4; ++r) {
      rs0 += w0[r];  rs1 += w0[4 + r];
      rs2 += w0[8 + r]; rs3 += w0[12 + r];
      rs0 += w1[r];  rs1 += w1[4 + r];
      rs2 += w1[8 + r]; rs3 += w1[12 + r];
    }
    float rs = (rs0 + rs1) + (rs2 + rs3);
    rs += __shfl_xor(rs, 32, 64);
    lsum += rs;

    uint32_t wd0[8], wd1[8];
#pragma unroll
    for (int j = 0; j < 8; ++j) {
      asm("v_cvt_pk_bf16_f32 %0, %1, %2" : "=v"(wd0[j]) : "v"(w0[2 * j]), "v"(w0[2 * j + 1]));
      asm("v_cvt_pk_bf16_f32 %0, %1, %2" : "=v"(wd1[j]) : "v"(w1[2 * j]), "v"(w1[2 * j + 1]));
    }
#pragma unroll
    for (int cc = 0; cc < 2; ++cc) {
      asm volatile("v_permlane32_swap_b32 %0, %1" : "+v"(wd0[4 * cc]), "+v"(wd0[4 * cc + 2]));
      asm volatile("v_permlane32_swap_b32 %0, %1" : "+v"(wd0[4 * cc + 1]), "+v"(wd0[4 * cc + 3]));
      asm volatile("v_permlane32_swap_b32 %0, %1" : "+v"(wd1[4 * cc]), "+v"(wd1[4 * cc + 2]));
      asm volatile("v_permlane32_swap_b32 %0, %1" : "+v"(wd1[4 * cc + 1]), "+v"(wd1[4 * cc + 3]));
    }

    __builtin_amdgcn_s_setprio(1);
#pragma unroll
    for (int kb = 0; kb < 4; ++kb) {
      union { uint32_t u[4]; bf16x8 v; } fu;
      const uint32_t* wds = (kb < 2) ? wd0 : wd1;
      const int cc = kb & 1;
      fu.u[0] = wds[4 * cc];     fu.u[1] = wds[4 * cc + 1];
      fu.u[2] = wds[4 * cc + 2]; fu.u[3] = wds[4 * cc + 3];
      const int gch = kb * 2 + hl;
      const bf16x8 v0 = *(const bf16x8*)((const char*)Vs[cur] +
                         l31 * 128 + ((gch ^ (l31 & 7)) << 4));
      const bf16x8 v1 = *(const bf16x8*)((const char*)Vs[cur] +
                         (32 + l31) * 128 + ((gch ^ ((32 + l31) & 7)) << 4));
      oacc0 = __builtin_amdgcn_mfma_f32_32x32x16_bf16(fu.v, v0, oacc0, 0, 0, 0);
      oacc1 = __builtin_amdgcn_mfma_f32_32x32x16_bf16(fu.v, v1, oacc1, 0, 0, 0);
    }
    __builtin_amdgcn_s_setprio(0);

    e0 = en0; e1 = en1;
    cur ^= 1;
  }

  red[wid][l31] = 1.0f / lsum;
  __syncthreads();
  unsigned short* aob = AO + ((size_t)b * 1024 + q0) * 768 + h * 64;
#pragma unroll
  for (int j = 0; j < 4; ++j) {
    const f32x4 lv = *(const f32x4*)&red[wid][8 * j + 4 * hl];
#pragma unroll
    for (int rr = 0; rr < 4; ++rr) {
      const int rowq = rr + 8 * j + 4 * hl;
      const int reg = 4 * j + rr;
      aob[rowq * 768 + l31]      = f2bf(oacc0[reg] * lv[rr]);
      aob[rowq * 768 + 32 + l31] = f2bf(oacc1[reg] * lv[rr]);
    }
  }
}

// ---------------- launch ----------------

extern "C" void kernel_launch(void* const* d_in, const int* in_sizes, int n_in,
                              void* d_out, int out_size, void* d_ws, size_t ws_size,
                              hipStream_t stream) {
  (void)in_sizes; (void)n_in; (void)out_size; (void)ws_size;
  const float* x = (const float*)d_in[0];
  const int* E = (const int*)d_in[1];
  const int* Mm = (const int*)d_in[2];
  const float* Wq = (const float*)d_in[3];
  const float* bq = (const float*)d_in[4];
  const float* Wk = (const float*)d_in[5];
  const float* bk = (const float*)d_in[6];
  const float* Wv = (const float*)d_in[7];
  const float* bv = (const float*)d_in[8];
  const float* Wo = (const float*)d_in[9];
  const float* bo = (const float*)d_in[10];
  const float* emb = (const float*)d_in[11];
  float* out = (float*)d_out;

  char* w = (char*)d_ws;
  unsigned short* x16 = (unsigned short*)w;  // reused as AO after gemm256_qkv
  unsigned short* AO = x16;
  w += (size_t)8192 * 768 * 2;
  unsigned short* wtqkv = (unsigned short*)w; w += (size_t)2304 * 768 * 2;
  unsigned short* wot = (unsigned short*)w;   w += (size_t)768 * 768 * 2;
  unsigned short* Qb = (unsigned short*)w;    w += (size_t)8 * 12 * 1024 * 64 * 2;
  unsigned short* Kb = (unsigned short*)w;    w += (size_t)8 * 12 * 1024 * 64 * 2;
  unsigned short* Vt = (unsigned short*)w;    w += (size_t)8 * 12 * 64 * 1024 * 2;
  uint8_t* E8L = (uint8_t*)w;                 w += (size_t)8 * 1024 * 1024;

  conv_x_k<<<6144, 256, 0, stream>>>(x, x16);
  conv_E_k<<<8192, 256, 0, stream>>>(E, Mm, E8L);
  transp_w_k<<<dim3(12, 12, 4), 256, 0, stream>>>(Wq, Wk, Wv, Wo, wtqkv, wot);
  gemm256_qkv<<<dim3(32, 9), 512, 0, stream>>>(x16, wtqkv, bq, bk, bv, Qb, Kb, Vt);
  attn_fused<<<768, 256, 0, stream>>>(Qb, Kb, Vt, E8L, emb, AO);
  gemm_out<<<dim3(64, 6), 256, 0, stream>>>(AO, wot, bo, out);
}

// Round 10
// 473.518 us; speedup vs baseline: 1.0007x; 1.0007x over previous
//
#include <hip/hip_runtime.h>
#include <stdint.h>

#define DEV __device__ __forceinline__

typedef __attribute__((ext_vector_type(8))) short bf16x8;
typedef __attribute__((ext_vector_type(4))) float f32x4;
typedef __attribute__((ext_vector_type(16))) float f32x16;

DEV unsigned short f2bf(float f) {
  union { float f; uint32_t u; } v; v.f = f;
  uint32_t r = v.u + 0x7fffu + ((v.u >> 16) & 1u);
  return (unsigned short)(r >> 16);
}

DEV void lds_load16(void* dst, const void* src) {
  __builtin_amdgcn_global_load_lds(
      (const __attribute__((address_space(1))) unsigned int*)src,
      (__attribute__((address_space(3))) unsigned int*)dst, 16, 0, 0);
}

// ---------------- prep kernels ----------------

__global__ void conv_x_k(const float* __restrict__ x, unsigned short* __restrict__ o) {
  const int i = blockIdx.x * 256 + threadIdx.x;  // 1572864 float4s
  const float4 v = ((const float4*)x)[i];
  ushort4 u;
  u.x = f2bf(v.x); u.y = f2bf(v.y); u.z = f2bf(v.z); u.w = f2bf(v.w);
  ((ushort4*)o)[i] = u;
}

// E (int32) -> lane-ordered masked-index records.
__global__ void conv_E_k(const int* __restrict__ E, const int* __restrict__ Mm,
                         uint8_t* __restrict__ E8L) {
  const int tid = blockIdx.x * 256 + threadIdx.x;  // 2097152
  const int k4 = tid & 255;
  const int q = (tid >> 8) & 1023;
  const int b = tid >> 18;
  const uint4 e = ((const uint4*)E)[tid];
  const int mq = Mm[b * 1024 + q];
  const int4 mk = *(const int4*)&Mm[b * 1024 + k4 * 4];
  uint32_t r;
  {
    const uint32_t b0 = (mq && mk.x) ? (e.x & 31u) : 32u;
    const uint32_t b1 = (mq && mk.y) ? (e.y & 31u) : 32u;
    const uint32_t b2 = (mq && mk.z) ? (e.z & 31u) : 32u;
    const uint32_t b3 = (mq && mk.w) ? (e.w & 31u) : 32u;
    r = b0 | (b1 << 8) | (b2 << 16) | (b3 << 24);
  }
  const int kt = k4 >> 4;
  const int k4t = k4 & 15;
  const int h = k4t & 1, c = (k4t >> 1) & 3, a = k4t >> 3;
  const int lane = (h << 5) | (q & 31);
  const int qw = q >> 5;
  const int j = a * 4 + c;
  const size_t rec = ((((size_t)b * 32 + qw) * 16 + kt) * 64 + lane) * 32 + j * 4;
  *(uint32_t*)(E8L + rec) = r;
}

// Wt[c][k] = W[k][c], bf16 pack. grid (12,12,4)
__global__ void transp_w_k(const float* __restrict__ Wq, const float* __restrict__ Wk,
                           const float* __restrict__ Wv, const float* __restrict__ Wo,
                           unsigned short* __restrict__ wtqkv, unsigned short* __restrict__ wot) {
  __shared__ float tile[64][65];
  const int z = blockIdx.z;
  const float* W = (z == 0) ? Wq : (z == 1) ? Wk : (z == 2) ? Wv : Wo;
  unsigned short* D = (z < 3) ? wtqkv + (size_t)z * 768 * 768 : wot;
  const int k0 = blockIdx.x * 64;
  const int c0 = blockIdx.y * 64;
  const int t = threadIdx.x;
#pragma unroll
  for (int i = 0; i < 4; ++i) {
    const int idx = i * 256 + t;
    const int r = idx >> 4;
    const int cq = (idx & 15) * 4;
    const float4 v = *(const float4*)&W[(k0 + r) * 768 + c0 + cq];
    tile[r][cq] = v.x; tile[r][cq + 1] = v.y; tile[r][cq + 2] = v.z; tile[r][cq + 3] = v.w;
  }
  __syncthreads();
#pragma unroll
  for (int i = 0; i < 4; ++i) {
    const int idx = i * 256 + t;
    const int c = idx >> 4;
    const int kq = (idx & 15) * 4;
    ushort4 u;
    u.x = f2bf(tile[kq][c]);     u.y = f2bf(tile[kq + 1][c]);
    u.z = f2bf(tile[kq + 2][c]); u.w = f2bf(tile[kq + 3][c]);
    *(ushort4*)&D[(c0 + c) * 768 + k0 + kq] = u;
  }
}

// ---------------- QKV GEMM: 256x256 tile, reg-staged, 8 waves ----------------
// A (8192,768) bf16; Bt = wtqkv (2304,768). Grid (32,9), block 512.
// Staging: global_load_dwordx4 -> regs (1 iter lead) -> ds_write_b128.
// One __syncthreads per K-step. Double-buffered 64 KB LDS.
// launch_bounds (512,4) => 2 blocks/CU co-resident: all 288 blocks resident,
// 2-deep block-level latency overlap per CU.
__global__ __launch_bounds__(512, 4)
void gemm256_qkv(const unsigned short* __restrict__ A, const unsigned short* __restrict__ Bt,
                 const float* __restrict__ b0, const float* __restrict__ b1,
                 const float* __restrict__ b2,
                 unsigned short* __restrict__ Qb, unsigned short* __restrict__ Kb,
                 unsigned short* __restrict__ Vt) {
  __shared__ __attribute__((aligned(16))) unsigned short lds[2][16384];  // [buf][A 8192 | B 8192]
  const int t = threadIdx.x;
  const int lane = t & 63;
  const int wid = t >> 6;        // 0..7
  const int wm2 = wid >> 2;      // 0..1 : 128-row band
  const int wn2 = wid & 3;       // 0..3 : 64-col band
  const int g = lane >> 4;
  const int c15 = lane & 15;

  const int m0 = blockIdx.x * 256;
  const int n0 = blockIdx.y * 256;

  const f32x4 Z4 = {0.f, 0.f, 0.f, 0.f};
  f32x4 acc[8][4];
#pragma unroll
  for (int m = 0; m < 8; ++m)
#pragma unroll
    for (int n = 0; n < 4; ++n) acc[m][n] = Z4;

  // staging geometry: thread loads row srow, k-chunks skc and skc+2 (8 elems each)
  const int srow = t & 255;
  const int skc = t >> 8;                       // 0 or 1
  const unsigned short* gA = A + (size_t)(m0 + srow) * 768 + skc * 8;
  const unsigned short* gB = Bt + (size_t)(n0 + srow) * 768 + skc * 8;
  const int u0e = (skc * 256 + srow) * 8;       // LDS elem: [kc][row] slots

  bf16x8 pA0, pA1, pB0, pB1;
  auto gload = [&](int kt) {
    const unsigned short* a = gA + kt * 32;
    const unsigned short* b = gB + kt * 32;
    pA0 = *(const bf16x8*)a;
    pA1 = *(const bf16x8*)(a + 16);   // k-chunk skc+2
    pB0 = *(const bf16x8*)b;
    pB1 = *(const bf16x8*)(b + 16);
  };
  auto swrite = [&](int buf) {
    *(bf16x8*)&lds[buf][u0e] = pA0;
    *(bf16x8*)&lds[buf][u0e + 4096] = pA1;
    *(bf16x8*)&lds[buf][8192 + u0e] = pB0;
    *(bf16x8*)&lds[buf][8192 + u0e + 4096] = pB1;
  };

  gload(0);
  swrite(0);           // tile 0 -> buf 0 (ds_write waits on its own loads)
  gload(1);            // tile 1 in regs, in flight during first compute
  __syncthreads();

  int cur = 0;
  for (int kt = 0; kt < 24; ++kt) {
    bf16x8 av[8], bvv[4];
#pragma unroll
    for (int m = 0; m < 8; ++m)
      av[m] = *(const bf16x8*)&lds[cur][g * 2048 + (wm2 * 128 + m * 16 + c15) * 8];
#pragma unroll
    for (int n = 0; n < 4; ++n)
      bvv[n] = *(const bf16x8*)&lds[cur][8192 + g * 2048 + (wn2 * 64 + n * 16 + c15) * 8];
#pragma unroll
    for (int m = 0; m < 8; ++m)
#pragma unroll
      for (int n = 0; n < 4; ++n)
        acc[m][n] = __builtin_amdgcn_mfma_f32_16x16x32_bf16(av[m], bvv[n], acc[m][n], 0, 0, 0);
    if (kt + 1 < 24) {
      swrite(cur ^ 1);               // write tile kt+1 (regs) to other buffer
      if (kt + 2 < 24) gload(kt + 2);  // issue loads for tile kt+2
    }
    __syncthreads();                 // reads of buf[cur] + writes of buf[cur^1] done
    cur ^= 1;
  }

  // epilogue: this wave's 64 cols = exactly one head of one of Q/K/V
  const int cwb = n0 + wn2 * 64;     // 64-aligned within one 768-mat
  const int mat = cwb / 768;
  const int cwm = cwb - mat * 768;
  const int hh = cwm >> 6;
  const float* bsel = (mat == 0) ? b0 : (mat == 1) ? b1 : b2;
  unsigned short* qk = (mat == 0) ? Qb : Kb;
#pragma unroll
  for (int n = 0; n < 4; ++n) {
    const int dd = n * 16 + c15;
    const float bval = bsel[hh * 64 + dd];
#pragma unroll
    for (int m = 0; m < 8; ++m) {
      const int r0 = m0 + wm2 * 128 + m * 16 + g * 4;
      const int bb = r0 >> 10;
      const int nn = r0 & 1023;
      if (mat < 2) {
        unsigned short* dst = qk + ((bb * 12 + hh) * 1024 + nn) * 64 + dd;
#pragma unroll
        for (int r = 0; r < 4; ++r) dst[r * 64] = f2bf(acc[m][n][r] + bval);
      } else {
        ushort4 w;
        w.x = f2bf(acc[m][n][0] + bval);
        w.y = f2bf(acc[m][n][1] + bval);
        w.z = f2bf(acc[m][n][2] + bval);
        w.w = f2bf(acc[m][n][3] + bval);
        *(ushort4*)&Vt[((bb * 12 + hh) * 64 + dd) * 1024 + nn] = w;
      }
    }
  }
}

// ---------------- output GEMM: 128x128, BK=32, 2D grid, 4 blocks/CU ----------------
__global__ __launch_bounds__(256, 4)
void gemm_out(const unsigned short* __restrict__ A, const unsigned short* __restrict__ Bt,
              const float* __restrict__ b0, float* __restrict__ Fo) {
  __shared__ __attribute__((aligned(16))) unsigned short lds[2][8192];
  const int t = threadIdx.x;
  const int lane = t & 63;
  const int wid = t >> 6;
  const int m0 = blockIdx.x * 128;
  const int n0 = blockIdx.y * 128;
  const int wm = (wid >> 1) * 64;
  const int wn = (wid & 1) * 64;
  const int srow = t & 127;
  const int sk8 = (t >> 7) * 8;

  const unsigned short* gA = A + (m0 + srow) * 768 + sk8;
  const unsigned short* gB = Bt + (n0 + srow) * 768 + sk8;

  const f32x4 Z4 = {0.f, 0.f, 0.f, 0.f};
  f32x4 acc[4][4];
#pragma unroll
  for (int m = 0; m < 4; ++m)
#pragma unroll
    for (int n = 0; n < 4; ++n) acc[m][n] = Z4;

  const int a_off = (lane >> 4) * 1024 + (wm + (lane & 15)) * 8;
  const int b_off = 4096 + (lane >> 4) * 1024 + (wn + (lane & 15)) * 8;

  auto stage = [&](int buf, int kt) {
    unsigned short* dA = &lds[buf][0] + wid * 512;
    unsigned short* dB = &lds[buf][4096] + wid * 512;
    const unsigned short* sA = gA + kt * 32;
    const unsigned short* sB = gB + kt * 32;
    lds_load16(dA, sA);
    lds_load16(dA + 2048, sA + 16);
    lds_load16(dB, sB);
    lds_load16(dB + 2048, sB + 16);
  };

  stage(0, 0);
  int cur = 0;
  for (int kt = 0; kt < 24; ++kt) {
    __syncthreads();
    if (kt + 1 < 24) stage(cur ^ 1, kt + 1);
    bf16x8 av[4], bvv[4];
#pragma unroll
    for (int m = 0; m < 4; ++m) av[m] = *(const bf16x8*)&lds[cur][a_off + m * 128];
#pragma unroll
    for (int n = 0; n < 4; ++n) bvv[n] = *(const bf16x8*)&lds[cur][b_off + n * 128];
#pragma unroll
    for (int m = 0; m < 4; ++m)
#pragma unroll
      for (int n = 0; n < 4; ++n)
        acc[m][n] = __builtin_amdgcn_mfma_f32_16x16x32_bf16(av[m], bvv[n], acc[m][n], 0, 0, 0);
    cur ^= 1;
  }

  const int g = lane >> 4;
  const int c15 = lane & 15;
#pragma unroll
  for (int n = 0; n < 4; ++n) {
    const int col = n0 + wn + n * 16 + c15;
    const float bval = b0[col];
#pragma unroll
    for (int m = 0; m < 4; ++m) {
      const int r0 = m0 + wm + m * 16 + g * 4;
#pragma unroll
      for (int r = 0; r < 4; ++r) Fo[(r0 + r) * 768 + col] = acc[m][n][r] + bval;
    }
  }
}

// ---------------- fused attention, swapped-QK^T 32x32 (m214 structure) ----------------
__global__ __launch_bounds__(256, 4)
void attn_fused(const unsigned short* __restrict__ Qb, const unsigned short* __restrict__ Kb,
                const unsigned short* __restrict__ Vt, const uint8_t* __restrict__ E8L,
                const float* __restrict__ emb, unsigned short* __restrict__ AO) {
  __shared__ __attribute__((aligned(16))) unsigned short Ks[2][4096];  // [krow64][d64] swz
  __shared__ __attribute__((aligned(16))) unsigned short Vs[2][4096];  // [d64][k64] swz
  __shared__ float ttab[33];
  __shared__ float red[4][32];

  const int t = threadIdx.x;
  const int lane = t & 63;
  const int wid = t >> 6;
  const int l31 = lane & 31;
  const int hl = lane >> 5;

  const int id = blockIdx.x;
  const int sw = (id & 7) * 96 + (id >> 3);
  const int b = sw / 96;
  const int rem = sw - b * 96;
  const int h = rem >> 3;
  const int qb = rem & 7;
  const int bh = b * 12 + h;
  const int qw = qb * 4 + wid;
  const int q0 = qw * 32;

  if (t < 33) ttab[t] = (t < 32) ? emb[t * 12 + h] * 1.44269504f : -1e30f;

  bf16x8 qf[4];
  {
    const unsigned short* qp = Qb + ((size_t)bh * 1024 + q0 + l31) * 64 + hl * 8;
#pragma unroll
    for (int dc = 0; dc < 4; ++dc) qf[dc] = *(const bf16x8*)(qp + dc * 16);
  }

  auto stageKV = [&](int buf, int kt) {
#pragma unroll
    for (int i = 0; i < 2; ++i) {
      const int c = i * 256 + t;
      const int row = c >> 3, c16 = c & 7;
      const int sc = (c16 ^ (row & 7)) * 8;
      lds_load16(&Ks[buf][i * 2048 + wid * 512],
                 Kb + ((size_t)bh * 1024 + kt * 64 + row) * 64 + sc);
      lds_load16(&Vs[buf][i * 2048 + wid * 512],
                 Vt + ((size_t)bh * 64 + row) * 1024 + kt * 64 + sc);
    }
  };

  const uint8_t* ebase = E8L + (((size_t)(b * 32 + qw)) * 16 * 64 + lane) * 32;

  stageKV(0, 0);
  uint4 e0 = *(const uint4*)(ebase);
  uint4 e1 = *(const uint4*)(ebase + 16);

  const f32x16 Z16 = {0.f};
  f32x16 oacc0 = Z16, oacc1 = Z16;
  float m = -3.0e38f, lsum = 0.f;
  int cur = 0;

  for (int kt = 0; kt < 16; ++kt) {
    __syncthreads();
    if (kt + 1 < 16) stageKV(cur ^ 1, kt + 1);
    uint4 en0 = e0, en1 = e1;  // defined on last iter
    if (kt + 1 < 16) {
      en0 = *(const uint4*)(ebase + (kt + 1) * 2048);
      en1 = *(const uint4*)(ebase + (kt + 1) * 2048 + 16);
    }

    f32x16 s0 = Z16, s1 = Z16;
    __builtin_amdgcn_s_setprio(1);
#pragma unroll
    for (int dc = 0; dc < 4; ++dc) {
      const int gch = (dc * 2 + hl);
      const bf16x8 a0 = *(const bf16x8*)((const char*)Ks[cur] +
                         l31 * 128 + ((gch ^ (l31 & 7)) << 4));
      const bf16x8 a1 = *(const bf16x8*)((const char*)Ks[cur] +
                         (32 + l31) * 128 + ((gch ^ ((32 + l31) & 7)) << 4));
      s0 = __builtin_amdgcn_mfma_f32_32x32x16_bf16(a0, qf[dc], s0, 0, 0, 0);
      s1 = __builtin_amdgcn_mfma_f32_32x32x16_bf16(a1, qf[dc], s1, 0, 0, 0);
    }
    __builtin_amdgcn_s_setprio(0);

    const uint32_t ed[8] = {e0.x, e0.y, e0.z, e0.w, e1.x, e1.y, e1.z, e1.w};
    float w0[16], w1[16];
#pragma unroll
    for (int r = 0; r < 16; ++r) {
      const uint32_t d0 = ed[r >> 2], d1 = ed[4 + (r >> 2)];
      const int sh = (r & 3) * 8;
      w0[r] = fmaf(s0[r], 0.18033688f, ttab[(d0 >> sh) & 0xffu]);
      w1[r] = fmaf(s1[r], 0.18033688f, ttab[(d1 >> sh) & 0xffu]);
    }

    float rm = fmaxf(w0[0], w1[0]);
#pragma unroll
    for (int r = 1; r < 16; ++r) rm = fmaxf(rm, fmaxf(w0[r], w1[r]));
    rm = fmaxf(rm, __shfl_xor(rm, 32, 64));

    if (__any(rm > m + 11.5415603f)) {
      const float mn = fmaxf(m, rm);
      const float scl = exp2f(m - mn);
      m = mn;
      lsum *= scl;
#pragma unroll
      for (int r = 0; r < 16; ++r) { oacc0[r] *= scl; oacc1[r] *= scl; }
    }

    float rs0 = 0.f, rs1 = 0.f, rs2 = 0.f, rs3 = 0.f;
#pragma unroll
    for (int r = 0; r < 16; ++r) {
      w0[r] = exp2f(w0[r] - m);
      w1[r] = exp2f(w1[r] - m);
    }
#pragma unroll
    for (int r = 0; r < 4; ++r) {
      rs0 += w0[r];  rs1 += w0[4 + r];
      rs2 += w0[8 + r]; rs3 += w0[12 + r];
      rs0 += w1[r];  rs1 += w1[4 + r];
      rs2 += w1[8 + r]; rs3 += w1[12 + r];
    }
    float rs = (rs0 + rs1) + (rs2 + rs3);
    rs += __shfl_xor(rs, 32, 64);
    lsum += rs;

    uint32_t wd0[8], wd1[8];
#pragma unroll
    for (int j = 0; j < 8; ++j) {
      asm("v_cvt_pk_bf16_f32 %0, %1, %2" : "=v"(wd0[j]) : "v"(w0[2 * j]), "v"(w0[2 * j + 1]));
      asm("v_cvt_pk_bf16_f32 %0, %1, %2" : "=v"(wd1[j]) : "v"(w1[2 * j]), "v"(w1[2 * j + 1]));
    }
#pragma unroll
    for (int cc = 0; cc < 2; ++cc) {
      asm volatile("v_permlane32_swap_b32 %0, %1" : "+v"(wd0[4 * cc]), "+v"(wd0[4 * cc + 2]));
      asm volatile("v_permlane32_swap_b32 %0, %1" : "+v"(wd0[4 * cc + 1]), "+v"(wd0[4 * cc + 3]));
      asm volatile("v_permlane32_swap_b32 %0, %1" : "+v"(wd1[4 * cc]), "+v"(wd1[4 * cc + 2]));
      asm volatile("v_permlane32_swap_b32 %0, %1" : "+v"(wd1[4 * cc + 1]), "+v"(wd1[4 * cc + 3]));
    }

    __builtin_amdgcn_s_setprio(1);
#pragma unroll
    for (int kb = 0; kb < 4; ++kb) {
      union { uint32_t u[4]; bf16x8 v; } fu;
      const uint32_t* wds = (kb < 2) ? wd0 : wd1;
      const int cc = kb & 1;
      fu.u[0] = wds[4 * cc];     fu.u[1] = wds[4 * cc + 1];
      fu.u[2] = wds[4 * cc + 2]; fu.u[3] = wds[4 * cc + 3];
      const int gch = kb * 2 + hl;
      const bf16x8 v0 = *(const bf16x8*)((const char*)Vs[cur] +
                         l31 * 128 + ((gch ^ (l31 & 7)) << 4));
      const bf16x8 v1 = *(const bf16x8*)((const char*)Vs[cur] +
                         (32 + l31) * 128 + ((gch ^ ((32 + l31) & 7)) << 4));
      oacc0 = __builtin_amdgcn_mfma_f32_32x32x16_bf16(fu.v, v0, oacc0, 0, 0, 0);
      oacc1 = __builtin_amdgcn_mfma_f32_32x32x16_bf16(fu.v, v1, oacc1, 0, 0, 0);
    }
    __builtin_amdgcn_s_setprio(0);

    e0 = en0; e1 = en1;
    cur ^= 1;
  }

  red[wid][l31] = 1.0f / lsum;
  __syncthreads();
  unsigned short* aob = AO + ((size_t)b * 1024 + q0) * 768 + h * 64;
#pragma unroll
  for (int j = 0; j < 4; ++j) {
    const f32x4 lv = *(const f32x4*)&red[wid][8 * j + 4 * hl];
#pragma unroll
    for (int rr = 0; rr < 4; ++rr) {
      const int rowq = rr + 8 * j + 4 * hl;
      const int reg = 4 * j + rr;
      aob[rowq * 768 + l31]      = f2bf(oacc0[reg] * lv[rr]);
      aob[rowq * 768 + 32 + l31] = f2bf(oacc1[reg] * lv[rr]);
    }
  }
}

// ---------------- launch ----------------

extern "C" void kernel_launch(void* const* d_in, const int* in_sizes, int n_in,
                              void* d_out, int out_size, void* d_ws, size_t ws_size,
                              hipStream_t stream) {
  (void)in_sizes; (void)n_in; (void)out_size; (void)ws_size;
  const float* x = (const float*)d_in[0];
  const int* E = (const int*)d_in[1];
  const int* Mm = (const int*)d_in[2];
  const float* Wq = (const float*)d_in[3];
  const float* bq = (const float*)d_in[4];
  const float* Wk = (const float*)d_in[5];
  const float* bk = (const float*)d_in[6];
  const float* Wv = (const float*)d_in[7];
  const float* bv = (const float*)d_in[8];
  const float* Wo = (const float*)d_in[9];
  const float* bo = (const float*)d_in[10];
  const float* emb = (const float*)d_in[11];
  float* out = (float*)d_out;

  char* w = (char*)d_ws;
  unsigned short* x16 = (unsigned short*)w;  // reused as AO after gemm256_qkv
  unsigned short* AO = x16;
  w += (size_t)8192 * 768 * 2;
  unsigned short* wtqkv = (unsigned short*)w; w += (size_t)2304 * 768 * 2;
  unsigned short* wot = (unsigned short*)w;   w += (size_t)768 * 768 * 2;
  unsigned short* Qb = (unsigned short*)w;    w += (size_t)8 * 12 * 1024 * 64 * 2;
  unsigned short* Kb = (unsigned short*)w;    w += (size_t)8 * 12 * 1024 * 64 * 2;
  unsigned short* Vt = (unsigned short*)w;    w += (size_t)8 * 12 * 64 * 1024 * 2;
  uint8_t* E8L = (uint8_t*)w;                 w += (size_t)8 * 1024 * 1024;

  conv_x_k<<<6144, 256, 0, stream>>>(x, x16);
  conv_E_k<<<8192, 256, 0, stream>>>(E, Mm, E8L);
  transp_w_k<<<dim3(12, 12, 4), 256, 0, stream>>>(Wq, Wk, Wv, Wo, wtqkv, wot);
  gemm256_qkv<<<dim3(32, 9), 512, 0, stream>>>(x16, wtqkv, bq, bk, bv, Qb, Kb, Vt);
  attn_fused<<<768, 256, 0, stream>>>(Qb, Kb, Vt, E8L, emb, AO);
  gemm_out<<<dim3(64, 6), 256, 0, stream>>>(AO, wot, bo, out);
}

// Round 11
// 473.511 us; speedup vs baseline: 1.0007x; 1.0000x over previous
//
#include <hip/hip_runtime.h>
#include <stdint.h>

#define DEV __device__ __forceinline__

typedef __attribute__((ext_vector_type(8))) short bf16x8;
typedef __attribute__((ext_vector_type(4))) float f32x4;
typedef __attribute__((ext_vector_type(16))) float f32x16;

DEV unsigned short f2bf(float f) {
  union { float f; uint32_t u; } v; v.f = f;
  uint32_t r = v.u + 0x7fffu + ((v.u >> 16) & 1u);
  return (unsigned short)(r >> 16);
}

DEV void lds_load16(void* dst, const void* src) {
  __builtin_amdgcn_global_load_lds(
      (const __attribute__((address_space(1))) unsigned int*)src,
      (__attribute__((address_space(3))) unsigned int*)dst, 16, 0, 0);
}

// ---------------- prep kernels ----------------

__global__ void conv_x_k(const float* __restrict__ x, unsigned short* __restrict__ o) {
  const int i = blockIdx.x * 256 + threadIdx.x;  // 1572864 float4s
  const float4 v = ((const float4*)x)[i];
  ushort4 u;
  u.x = f2bf(v.x); u.y = f2bf(v.y); u.z = f2bf(v.z); u.w = f2bf(v.w);
  ((ushort4*)o)[i] = u;
}

// E (int32) -> lane-ordered masked-index records.
__global__ void conv_E_k(const int* __restrict__ E, const int* __restrict__ Mm,
                         uint8_t* __restrict__ E8L) {
  const int tid = blockIdx.x * 256 + threadIdx.x;  // 2097152
  const int k4 = tid & 255;
  const int q = (tid >> 8) & 1023;
  const int b = tid >> 18;
  const uint4 e = ((const uint4*)E)[tid];
  const int mq = Mm[b * 1024 + q];
  const int4 mk = *(const int4*)&Mm[b * 1024 + k4 * 4];
  uint32_t r;
  {
    const uint32_t b0 = (mq && mk.x) ? (e.x & 31u) : 32u;
    const uint32_t b1 = (mq && mk.y) ? (e.y & 31u) : 32u;
    const uint32_t b2 = (mq && mk.z) ? (e.z & 31u) : 32u;
    const uint32_t b3 = (mq && mk.w) ? (e.w & 31u) : 32u;
    r = b0 | (b1 << 8) | (b2 << 16) | (b3 << 24);
  }
  const int kt = k4 >> 4;
  const int k4t = k4 & 15;
  const int h = k4t & 1, c = (k4t >> 1) & 3, a = k4t >> 3;
  const int lane = (h << 5) | (q & 31);
  const int qw = q >> 5;
  const int j = a * 4 + c;
  const size_t rec = ((((size_t)b * 32 + qw) * 16 + kt) * 64 + lane) * 32 + j * 4;
  *(uint32_t*)(E8L + rec) = r;
}

// Wt[c][k] = W[k][c], bf16 pack. grid (12,12,4)
__global__ void transp_w_k(const float* __restrict__ Wq, const float* __restrict__ Wk,
                           const float* __restrict__ Wv, const float* __restrict__ Wo,
                           unsigned short* __restrict__ wtqkv, unsigned short* __restrict__ wot) {
  __shared__ float tile[64][65];
  const int z = blockIdx.z;
  const float* W = (z == 0) ? Wq : (z == 1) ? Wk : (z == 2) ? Wv : Wo;
  unsigned short* D = (z < 3) ? wtqkv + (size_t)z * 768 * 768 : wot;
  const int k0 = blockIdx.x * 64;
  const int c0 = blockIdx.y * 64;
  const int t = threadIdx.x;
#pragma unroll
  for (int i = 0; i < 4; ++i) {
    const int idx = i * 256 + t;
    const int r = idx >> 4;
    const int cq = (idx & 15) * 4;
    const float4 v = *(const float4*)&W[(k0 + r) * 768 + c0 + cq];
    tile[r][cq] = v.x; tile[r][cq + 1] = v.y; tile[r][cq + 2] = v.z; tile[r][cq + 3] = v.w;
  }
  __syncthreads();
#pragma unroll
  for (int i = 0; i < 4; ++i) {
    const int idx = i * 256 + t;
    const int c = idx >> 4;
    const int kq = (idx & 15) * 4;
    ushort4 u;
    u.x = f2bf(tile[kq][c]);     u.y = f2bf(tile[kq + 1][c]);
    u.z = f2bf(tile[kq + 2][c]); u.w = f2bf(tile[kq + 3][c]);
    *(ushort4*)&D[(c0 + c) * 768 + k0 + kq] = u;
  }
}

// ---------------- QKV GEMM: 256x256 tile, reg-staged, 8 waves ----------------
// A (8192,768) bf16; Bt = wtqkv (2304,768). Grid (32,9), block 512.
// Staging: global_load_dwordx4 -> regs (1 iter lead) -> ds_write_b128.
// One __syncthreads per K-step. Double-buffered 64 KB LDS.
// launch_bounds (512,4) => 2 blocks/CU co-resident: all 288 blocks resident,
// 2-deep block-level latency overlap per CU.
__global__ __launch_bounds__(512, 4)
void gemm256_qkv(const unsigned short* __restrict__ A, const unsigned short* __restrict__ Bt,
                 const float* __restrict__ b0, const float* __restrict__ b1,
                 const float* __restrict__ b2,
                 unsigned short* __restrict__ Qb, unsigned short* __restrict__ Kb,
                 unsigned short* __restrict__ Vt) {
  __shared__ __attribute__((aligned(16))) unsigned short lds[2][16384];  // [buf][A 8192 | B 8192]
  const int t = threadIdx.x;
  const int lane = t & 63;
  const int wid = t >> 6;        // 0..7
  const int wm2 = wid >> 2;      // 0..1 : 128-row band
  const int wn2 = wid & 3;       // 0..3 : 64-col band
  const int g = lane >> 4;
  const int c15 = lane & 15;

  const int m0 = blockIdx.x * 256;
  const int n0 = blockIdx.y * 256;

  const f32x4 Z4 = {0.f, 0.f, 0.f, 0.f};
  f32x4 acc[8][4];
#pragma unroll
  for (int m = 0; m < 8; ++m)
#pragma unroll
    for (int n = 0; n < 4; ++n) acc[m][n] = Z4;

  // staging geometry: thread loads row srow, k-chunks skc and skc+2 (8 elems each)
  const int srow = t & 255;
  const int skc = t >> 8;                       // 0 or 1
  const unsigned short* gA = A + (size_t)(m0 + srow) * 768 + skc * 8;
  const unsigned short* gB = Bt + (size_t)(n0 + srow) * 768 + skc * 8;
  const int u0e = (skc * 256 + srow) * 8;       // LDS elem: [kc][row] slots

  bf16x8 pA0, pA1, pB0, pB1;
  auto gload = [&](int kt) {
    const unsigned short* a = gA + kt * 32;
    const unsigned short* b = gB + kt * 32;
    pA0 = *(const bf16x8*)a;
    pA1 = *(const bf16x8*)(a + 16);   // k-chunk skc+2
    pB0 = *(const bf16x8*)b;
    pB1 = *(const bf16x8*)(b + 16);
  };
  auto swrite = [&](int buf) {
    *(bf16x8*)&lds[buf][u0e] = pA0;
    *(bf16x8*)&lds[buf][u0e + 4096] = pA1;
    *(bf16x8*)&lds[buf][8192 + u0e] = pB0;
    *(bf16x8*)&lds[buf][8192 + u0e + 4096] = pB1;
  };

  gload(0);
  swrite(0);           // tile 0 -> buf 0 (ds_write waits on its own loads)
  gload(1);            // tile 1 in regs, in flight during first compute
  __syncthreads();

  int cur = 0;
  for (int kt = 0; kt < 24; ++kt) {
    bf16x8 av[8], bvv[4];
#pragma unroll
    for (int m = 0; m < 8; ++m)
      av[m] = *(const bf16x8*)&lds[cur][g * 2048 + (wm2 * 128 + m * 16 + c15) * 8];
#pragma unroll
    for (int n = 0; n < 4; ++n)
      bvv[n] = *(const bf16x8*)&lds[cur][8192 + g * 2048 + (wn2 * 64 + n * 16 + c15) * 8];
#pragma unroll
    for (int m = 0; m < 8; ++m)
#pragma unroll
      for (int n = 0; n < 4; ++n)
        acc[m][n] = __builtin_amdgcn_mfma_f32_16x16x32_bf16(av[m], bvv[n], acc[m][n], 0, 0, 0);
    if (kt + 1 < 24) {
      swrite(cur ^ 1);               // write tile kt+1 (regs) to other buffer
      if (kt + 2 < 24) gload(kt + 2);  // issue loads for tile kt+2
    }
    __syncthreads();                 // reads of buf[cur] + writes of buf[cur^1] done
    cur ^= 1;
  }

  // epilogue: this wave's 64 cols = exactly one head of one of Q/K/V
  const int cwb = n0 + wn2 * 64;     // 64-aligned within one 768-mat
  const int mat = cwb / 768;
  const int cwm = cwb - mat * 768;
  const int hh = cwm >> 6;
  const float* bsel = (mat == 0) ? b0 : (mat == 1) ? b1 : b2;
  unsigned short* qk = (mat == 0) ? Qb : Kb;
#pragma unroll
  for (int n = 0; n < 4; ++n) {
    const int dd = n * 16 + c15;
    const float bval = bsel[hh * 64 + dd];
#pragma unroll
    for (int m = 0; m < 8; ++m) {
      const int r0 = m0 + wm2 * 128 + m * 16 + g * 4;
      const int bb = r0 >> 10;
      const int nn = r0 & 1023;
      if (mat < 2) {
        unsigned short* dst = qk + ((bb * 12 + hh) * 1024 + nn) * 64 + dd;
#pragma unroll
        for (int r = 0; r < 4; ++r) dst[r * 64] = f2bf(acc[m][n][r] + bval);
      } else {
        ushort4 w;
        w.x = f2bf(acc[m][n][0] + bval);
        w.y = f2bf(acc[m][n][1] + bval);
        w.z = f2bf(acc[m][n][2] + bval);
        w.w = f2bf(acc[m][n][3] + bval);
        *(ushort4*)&Vt[((bb * 12 + hh) * 64 + dd) * 1024 + nn] = w;
      }
    }
  }
}

// ---------------- output GEMM: 128x128, BK=32, 2D grid, 4 blocks/CU ----------------
__global__ __launch_bounds__(256, 4)
void gemm_out(const unsigned short* __restrict__ A, const unsigned short* __restrict__ Bt,
              const float* __restrict__ b0, float* __restrict__ Fo) {
  __shared__ __attribute__((aligned(16))) unsigned short lds[2][8192];
  const int t = threadIdx.x;
  const int lane = t & 63;
  const int wid = t >> 6;
  const int m0 = blockIdx.x * 128;
  const int n0 = blockIdx.y * 128;
  const int wm = (wid >> 1) * 64;
  const int wn = (wid & 1) * 64;
  const int srow = t & 127;
  const int sk8 = (t >> 7) * 8;

  const unsigned short* gA = A + (m0 + srow) * 768 + sk8;
  const unsigned short* gB = Bt + (n0 + srow) * 768 + sk8;

  const f32x4 Z4 = {0.f, 0.f, 0.f, 0.f};
  f32x4 acc[4][4];
#pragma unroll
  for (int m = 0; m < 4; ++m)
#pragma unroll
    for (int n = 0; n < 4; ++n) acc[m][n] = Z4;

  const int a_off = (lane >> 4) * 1024 + (wm + (lane & 15)) * 8;
  const int b_off = 4096 + (lane >> 4) * 1024 + (wn + (lane & 15)) * 8;

  auto stage = [&](int buf, int kt) {
    unsigned short* dA = &lds[buf][0] + wid * 512;
    unsigned short* dB = &lds[buf][4096] + wid * 512;
    const unsigned short* sA = gA + kt * 32;
    const unsigned short* sB = gB + kt * 32;
    lds_load16(dA, sA);
    lds_load16(dA + 2048, sA + 16);
    lds_load16(dB, sB);
    lds_load16(dB + 2048, sB + 16);
  };

  stage(0, 0);
  int cur = 0;
  for (int kt = 0; kt < 24; ++kt) {
    __syncthreads();
    if (kt + 1 < 24) stage(cur ^ 1, kt + 1);
    bf16x8 av[4], bvv[4];
#pragma unroll
    for (int m = 0; m < 4; ++m) av[m] = *(const bf16x8*)&lds[cur][a_off + m * 128];
#pragma unroll
    for (int n = 0; n < 4; ++n) bvv[n] = *(const bf16x8*)&lds[cur][b_off + n * 128];
#pragma unroll
    for (int m = 0; m < 4; ++m)
#pragma unroll
      for (int n = 0; n < 4; ++n)
        acc[m][n] = __builtin_amdgcn_mfma_f32_16x16x32_bf16(av[m], bvv[n], acc[m][n], 0, 0, 0);
    cur ^= 1;
  }

  const int g = lane >> 4;
  const int c15 = lane & 15;
#pragma unroll
  for (int n = 0; n < 4; ++n) {
    const int col = n0 + wn + n * 16 + c15;
    const float bval = b0[col];
#pragma unroll
    for (int m = 0; m < 4; ++m) {
      const int r0 = m0 + wm + m * 16 + g * 4;
#pragma unroll
      for (int r = 0; r < 4; ++r) Fo[(r0 + r) * 768 + col] = acc[m][n][r] + bval;
    }
  }
}

// ---------------- fused attention, swapped-QK^T 32x32 (m214 structure) ----------------
__global__ __launch_bounds__(256, 4)
void attn_fused(const unsigned short* __restrict__ Qb, const unsigned short* __restrict__ Kb,
                const unsigned short* __restrict__ Vt, const uint8_t* __restrict__ E8L,
                const float* __restrict__ emb, unsigned short* __restrict__ AO) {
  __shared__ __attribute__((aligned(16))) unsigned short Ks[2][4096];  // [krow64][d64] swz
  __shared__ __attribute__((aligned(16))) unsigned short Vs[2][4096];  // [d64][k64] swz
  __shared__ float ttab[33];
  __shared__ float red[4][32];

  const int t = threadIdx.x;
  const int lane = t & 63;
  const int wid = t >> 6;
  const int l31 = lane & 31;
  const int hl = lane >> 5;

  const int id = blockIdx.x;
  const int sw = (id & 7) * 96 + (id >> 3);
  const int b = sw / 96;
  const int rem = sw - b * 96;
  const int h = rem >> 3;
  const int qb = rem & 7;
  const int bh = b * 12 + h;
  const int qw = qb * 4 + wid;
  const int q0 = qw * 32;

  if (t < 33) ttab[t] = (t < 32) ? emb[t * 12 + h] * 1.44269504f : -1e30f;

  bf16x8 qf[4];
  {
    const unsigned short* qp = Qb + ((size_t)bh * 1024 + q0 + l31) * 64 + hl * 8;
#pragma unroll
    for (int dc = 0; dc < 4; ++dc) qf[dc] = *(const bf16x8*)(qp + dc * 16);
  }

  auto stageKV = [&](int buf, int kt) {
#pragma unroll
    for (int i = 0; i < 2; ++i) {
      const int c = i * 256 + t;
      const int row = c >> 3, c16 = c & 7;
      const int sc = (c16 ^ (row & 7)) * 8;
      lds_load16(&Ks[buf][i * 2048 + wid * 512],
                 Kb + ((size_t)bh * 1024 + kt * 64 + row) * 64 + sc);
      lds_load16(&Vs[buf][i * 2048 + wid * 512],
                 Vt + ((size_t)bh * 64 + row) * 1024 + kt * 64 + sc);
    }
  };

  const uint8_t* ebase = E8L + (((size_t)(b * 32 + qw)) * 16 * 64 + lane) * 32;

  stageKV(0, 0);
  uint4 e0 = *(const uint4*)(ebase);
  uint4 e1 = *(const uint4*)(ebase + 16);

  const f32x16 Z16 = {0.f};
  f32x16 oacc0 = Z16, oacc1 = Z16;
  float m = -3.0e38f, lsum = 0.f;
  int cur = 0;

  for (int kt = 0; kt < 16; ++kt) {
    __syncthreads();
    if (kt + 1 < 16) stageKV(cur ^ 1, kt + 1);
    uint4 en0 = e0, en1 = e1;  // defined on last iter
    if (kt + 1 < 16) {
      en0 = *(const uint4*)(ebase + (kt + 1) * 2048);
      en1 = *(const uint4*)(ebase + (kt + 1) * 2048 + 16);
    }

    f32x16 s0 = Z16, s1 = Z16;
    __builtin_amdgcn_s_setprio(1);
#pragma unroll
    for (int dc = 0; dc < 4; ++dc) {
      const int gch = (dc * 2 + hl);
      const bf16x8 a0 = *(const bf16x8*)((const char*)Ks[cur] +
                         l31 * 128 + ((gch ^ (l31 & 7)) << 4));
      const bf16x8 a1 = *(const bf16x8*)((const char*)Ks[cur] +
                         (32 + l31) * 128 + ((gch ^ ((32 + l31) & 7)) << 4));
      s0 = __builtin_amdgcn_mfma_f32_32x32x16_bf16(a0, qf[dc], s0, 0, 0, 0);
      s1 = __builtin_amdgcn_mfma_f32_32x32x16_bf16(a1, qf[dc], s1, 0, 0, 0);
    }
    __builtin_amdgcn_s_setprio(0);

    const uint32_t ed[8] = {e0.x, e0.y, e0.z, e0.w, e1.x, e1.y, e1.z, e1.w};
    float w0[16], w1[16];
#pragma unroll
    for (int r = 0; r < 16; ++r) {
      const uint32_t d0 = ed[r >> 2], d1 = ed[4 + (r >> 2)];
      const int sh = (r & 3) * 8;
      w0[r] = fmaf(s0[r], 0.18033688f, ttab[(d0 >> sh) & 0xffu]);
      w1[r] = fmaf(s1[r], 0.18033688f, ttab[(d1 >> sh) & 0xffu]);
    }

    float rm = fmaxf(w0[0], w1[0]);
#pragma unroll
    for (int r = 1; r < 16; ++r) rm = fmaxf(rm, fmaxf(w0[r], w1[r]));
    rm = fmaxf(rm, __shfl_xor(rm, 32, 64));

    if (__any(rm > m + 11.5415603f)) {
      const float mn = fmaxf(m, rm);
      const float scl = exp2f(m - mn);
      m = mn;
      lsum *= scl;
#pragma unroll
      for (int r = 0; r < 16; ++r) { oacc0[r] *= scl; oacc1[r] *= scl; }
    }

    float rs0 = 0.f, rs1 = 0.f, rs2 = 0.f, rs3 = 0.f;
#pragma unroll
    for (int r = 0; r < 16; ++r) {
      w0[r] = exp2f(w0[r] - m);
      w1[r] = exp2f(w1[r] - m);
    }
#pragma unroll
    for (int r = 0; r < 4; ++r) {
      rs0 += w0[r];  rs1 += w0[4 + r];
      rs2 += w0[8 + r]; rs3 += w0[12 + r];
      rs0 += w1[r];  rs1 += w1[4 + r];
      rs2 += w1[8 + r]; rs3 += w1[12 + r];
    }
    float rs = (rs0 + rs1) + (rs2 + rs3);
    rs += __shfl_xor(rs, 32, 64);
    lsum += rs;

    uint32_t wd0[8], wd1[8];
#pragma unroll
    for (int j = 0; j < 8; ++j) {
      asm("v_cvt_pk_bf16_f32 %0, %1, %2" : "=v"(wd0[j]) : "v"(w0[2 * j]), "v"(w0[2 * j + 1]));
      asm("v_cvt_pk_bf16_f32 %0, %1, %2" : "=v"(wd1[j]) : "v"(w1[2 * j]), "v"(w1[2 * j + 1]));
    }
#pragma unroll
    for (int cc = 0; cc < 2; ++cc) {
      asm volatile("v_permlane32_swap_b32 %0, %1" : "+v"(wd0[4 * cc]), "+v"(wd0[4 * cc + 2]));
      asm volatile("v_permlane32_swap_b32 %0, %1" : "+v"(wd0[4 * cc + 1]), "+v"(wd0[4 * cc + 3]));
      asm volatile("v_permlane32_swap_b32 %0, %1" : "+v"(wd1[4 * cc]), "+v"(wd1[4 * cc + 2]));
      asm volatile("v_permlane32_swap_b32 %0, %1" : "+v"(wd1[4 * cc + 1]), "+v"(wd1[4 * cc + 3]));
    }

    __builtin_amdgcn_s_setprio(1);
#pragma unroll
    for (int kb = 0; kb < 4; ++kb) {
      union { uint32_t u[4]; bf16x8 v; } fu;
      const uint32_t* wds = (kb < 2) ? wd0 : wd1;
      const int cc = kb & 1;
      fu.u[0] = wds[4 * cc];     fu.u[1] = wds[4 * cc + 1];
      fu.u[2] = wds[4 * cc + 2]; fu.u[3] = wds[4 * cc + 3];
      const int gch = kb * 2 + hl;
      const bf16x8 v0 = *(const bf16x8*)((const char*)Vs[cur] +
                         l31 * 128 + ((gch ^ (l31 & 7)) << 4));
      const bf16x8 v1 = *(const bf16x8*)((const char*)Vs[cur] +
                         (32 + l31) * 128 + ((gch ^ ((32 + l31) & 7)) << 4));
      oacc0 = __builtin_amdgcn_mfma_f32_32x32x16_bf16(fu.v, v0, oacc0, 0, 0, 0);
      oacc1 = __builtin_amdgcn_mfma_f32_32x32x16_bf16(fu.v, v1, oacc1, 0, 0, 0);
    }
    __builtin_amdgcn_s_setprio(0);

    e0 = en0; e1 = en1;
    cur ^= 1;
  }

  red[wid][l31] = 1.0f / lsum;
  __syncthreads();
  unsigned short* aob = AO + ((size_t)b * 1024 + q0) * 768 + h * 64;
#pragma unroll
  for (int j = 0; j < 4; ++j) {
    const f32x4 lv = *(const f32x4*)&red[wid][8 * j + 4 * hl];
#pragma unroll
    for (int rr = 0; rr < 4; ++rr) {
      const int rowq = rr + 8 * j + 4 * hl;
      const int reg = 4 * j + rr;
      aob[rowq * 768 + l31]      = f2bf(oacc0[reg] * lv[rr]);
      aob[rowq * 768 + 32 + l31] = f2bf(oacc1[reg] * lv[rr]);
    }
  }
}

// ---------------- launch ----------------

extern "C" void kernel_launch(void* const* d_in, const int* in_sizes, int n_in,
                              void* d_out, int out_size, void* d_ws, size_t ws_size,
                              hipStream_t stream) {
  (void)in_sizes; (void)n_in; (void)out_size; (void)ws_size;
  const float* x = (const float*)d_in[0];
  const int* E = (const int*)d_in[1];
  const int* Mm = (const int*)d_in[2];
  const float* Wq = (const float*)d_in[3];
  const float* bq = (const float*)d_in[4];
  const float* Wk = (const float*)d_in[5];
  const float* bk = (const float*)d_in[6];
  const float* Wv = (const float*)d_in[7];
  const float* bv = (const float*)d_in[8];
  const float* Wo = (const float*)d_in[9];
  const float* bo = (const float*)d_in[10];
  const float* emb = (const float*)d_in[11];
  float* out = (float*)d_out;

  char* w = (char*)d_ws;
  unsigned short* x16 = (unsigned short*)w;  // reused as AO after gemm256_qkv
  unsigned short* AO = x16;
  w += (size_t)8192 * 768 * 2;
  unsigned short* wtqkv = (unsigned short*)w; w += (size_t)2304 * 768 * 2;
  unsigned short* wot = (unsigned short*)w;   w += (size_t)768 * 768 * 2;
  unsigned short* Qb = (unsigned short*)w;    w += (size_t)8 * 12 * 1024 * 64 * 2;
  unsigned short* Kb = (unsigned short*)w;    w += (size_t)8 * 12 * 1024 * 64 * 2;
  unsigned short* Vt = (unsigned short*)w;    w += (size_t)8 * 12 * 64 * 1024 * 2;
  uint8_t* E8L = (uint8_t*)w;                 w += (size_t)8 * 1024 * 1024;

  conv_x_k<<<6144, 256, 0, stream>>>(x, x16);
  conv_E_k<<<8192, 256, 0, stream>>>(E, Mm, E8L);
  transp_w_k<<<dim3(12, 12, 4), 256, 0, stream>>>(Wq, Wk, Wv, Wo, wtqkv, wot);
  gemm256_qkv<<<dim3(32, 9), 512, 0, stream>>>(x16, wtqkv, bq, bk, bv, Qb, Kb, Vt);
  attn_fused<<<768, 256, 0, stream>>>(Qb, Kb, Vt, E8L, emb, AO);
  gemm_out<<<dim3(64, 6), 256, 0, stream>>>(AO, wot, bo, out);
}

// Round 12
// 182.628 us; speedup vs baseline: 2.5946x; 2.5928x over previous
//
#include <hip/hip_runtime.h>
#include <stdint.h>

#define DEV __device__ __forceinline__

typedef __attribute__((ext_vector_type(8))) short bf16x8;
typedef __attribute__((ext_vector_type(4))) float f32x4;
typedef __attribute__((ext_vector_type(16))) float f32x16;

DEV unsigned short f2bf(float f) {
  union { float f; uint32_t u; } v; v.f = f;
  uint32_t r = v.u + 0x7fffu + ((v.u >> 16) & 1u);
  return (unsigned short)(r >> 16);
}

DEV void lds_load16(void* dst, const void* src) {
  __builtin_amdgcn_global_load_lds(
      (const __attribute__((address_space(1))) unsigned int*)src,
      (__attribute__((address_space(3))) unsigned int*)dst, 16, 0, 0);
}

// ---------------- prep kernels ----------------

__global__ void conv_x_k(const float* __restrict__ x, unsigned short* __restrict__ o) {
  const int i = blockIdx.x * 256 + threadIdx.x;  // 1572864 float4s
  const float4 v = ((const float4*)x)[i];
  ushort4 u;
  u.x = f2bf(v.x); u.y = f2bf(v.y); u.z = f2bf(v.z); u.w = f2bf(v.w);
  ((ushort4*)o)[i] = u;
}

// E (int32) -> lane-ordered masked-index records.
__global__ void conv_E_k(const int* __restrict__ E, const int* __restrict__ Mm,
                         uint8_t* __restrict__ E8L) {
  const int tid = blockIdx.x * 256 + threadIdx.x;  // 2097152
  const int k4 = tid & 255;
  const int q = (tid >> 8) & 1023;
  const int b = tid >> 18;
  const uint4 e = ((const uint4*)E)[tid];
  const int mq = Mm[b * 1024 + q];
  const int4 mk = *(const int4*)&Mm[b * 1024 + k4 * 4];
  uint32_t r;
  {
    const uint32_t b0 = (mq && mk.x) ? (e.x & 31u) : 32u;
    const uint32_t b1 = (mq && mk.y) ? (e.y & 31u) : 32u;
    const uint32_t b2 = (mq && mk.z) ? (e.z & 31u) : 32u;
    const uint32_t b3 = (mq && mk.w) ? (e.w & 31u) : 32u;
    r = b0 | (b1 << 8) | (b2 << 16) | (b3 << 24);
  }
  const int kt = k4 >> 4;
  const int k4t = k4 & 15;
  const int h = k4t & 1, c = (k4t >> 1) & 3, a = k4t >> 3;
  const int lane = (h << 5) | (q & 31);
  const int qw = q >> 5;
  const int j = a * 4 + c;
  const size_t rec = ((((size_t)b * 32 + qw) * 16 + kt) * 64 + lane) * 32 + j * 4;
  *(uint32_t*)(E8L + rec) = r;
}

// Wt[c][k] = W[k][c], bf16 pack. grid (12,12,4)
__global__ void transp_w_k(const float* __restrict__ Wq, const float* __restrict__ Wk,
                           const float* __restrict__ Wv, const float* __restrict__ Wo,
                           unsigned short* __restrict__ wtqkv, unsigned short* __restrict__ wot) {
  __shared__ float tile[64][65];
  const int z = blockIdx.z;
  const float* W = (z == 0) ? Wq : (z == 1) ? Wk : (z == 2) ? Wv : Wo;
  unsigned short* D = (z < 3) ? wtqkv + (size_t)z * 768 * 768 : wot;
  const int k0 = blockIdx.x * 64;
  const int c0 = blockIdx.y * 64;
  const int t = threadIdx.x;
#pragma unroll
  for (int i = 0; i < 4; ++i) {
    const int idx = i * 256 + t;
    const int r = idx >> 4;
    const int cq = (idx & 15) * 4;
    const float4 v = *(const float4*)&W[(k0 + r) * 768 + c0 + cq];
    tile[r][cq] = v.x; tile[r][cq + 1] = v.y; tile[r][cq + 2] = v.z; tile[r][cq + 3] = v.w;
  }
  __syncthreads();
#pragma unroll
  for (int i = 0; i < 4; ++i) {
    const int idx = i * 256 + t;
    const int c = idx >> 4;
    const int kq = (idx & 15) * 4;
    ushort4 u;
    u.x = f2bf(tile[kq][c]);     u.y = f2bf(tile[kq + 1][c]);
    u.z = f2bf(tile[kq + 2][c]); u.w = f2bf(tile[kq + 3][c]);
    *(ushort4*)&D[(c0 + c) * 768 + k0 + kq] = u;
  }
}

// ---------------- QKV GEMM: 256x256 tile, reg-staged, 8 waves ----------------
// A (8192,768) bf16; Bt = wtqkv (2304,768). Grid (32,9), block 512.
// Staging: global_load_dwordx4 -> regs (1 iter lead) -> ds_write_b128.
// One __syncthreads per K-step. Double-buffered 64 KB LDS.
// launch_bounds (512,2): 2 blocks/CU (CUDA semantics: min blocks/multiproc),
// VGPR cap 128 -> kernel's 112 VGPR fits WITHOUT spilling (r11: (512,4) forced
// 64 VGPR -> 735 MB scratch traffic, 380 us).
__global__ __launch_bounds__(512, 2)
void gemm256_qkv(const unsigned short* __restrict__ A, const unsigned short* __restrict__ Bt,
                 const float* __restrict__ b0, const float* __restrict__ b1,
                 const float* __restrict__ b2,
                 unsigned short* __restrict__ Qb, unsigned short* __restrict__ Kb,
                 unsigned short* __restrict__ Vt) {
  __shared__ __attribute__((aligned(16))) unsigned short lds[2][16384];  // [buf][A 8192 | B 8192]
  const int t = threadIdx.x;
  const int lane = t & 63;
  const int wid = t >> 6;        // 0..7
  const int wm2 = wid >> 2;      // 0..1 : 128-row band
  const int wn2 = wid & 3;       // 0..3 : 64-col band
  const int g = lane >> 4;
  const int c15 = lane & 15;

  const int m0 = blockIdx.x * 256;
  const int n0 = blockIdx.y * 256;

  const f32x4 Z4 = {0.f, 0.f, 0.f, 0.f};
  f32x4 acc[8][4];
#pragma unroll
  for (int m = 0; m < 8; ++m)
#pragma unroll
    for (int n = 0; n < 4; ++n) acc[m][n] = Z4;

  // staging geometry: thread loads row srow, k-chunks skc and skc+2 (8 elems each)
  const int srow = t & 255;
  const int skc = t >> 8;                       // 0 or 1
  const unsigned short* gA = A + (size_t)(m0 + srow) * 768 + skc * 8;
  const unsigned short* gB = Bt + (size_t)(n0 + srow) * 768 + skc * 8;
  const int u0e = (skc * 256 + srow) * 8;       // LDS elem: [kc][row] slots

  bf16x8 pA0, pA1, pB0, pB1;
  auto gload = [&](int kt) {
    const unsigned short* a = gA + kt * 32;
    const unsigned short* b = gB + kt * 32;
    pA0 = *(const bf16x8*)a;
    pA1 = *(const bf16x8*)(a + 16);   // k-chunk skc+2
    pB0 = *(const bf16x8*)b;
    pB1 = *(const bf16x8*)(b + 16);
  };
  auto swrite = [&](int buf) {
    *(bf16x8*)&lds[buf][u0e] = pA0;
    *(bf16x8*)&lds[buf][u0e + 4096] = pA1;
    *(bf16x8*)&lds[buf][8192 + u0e] = pB0;
    *(bf16x8*)&lds[buf][8192 + u0e + 4096] = pB1;
  };

  gload(0);
  swrite(0);           // tile 0 -> buf 0 (ds_write waits on its own loads)
  gload(1);            // tile 1 in regs, in flight during first compute
  __syncthreads();

  int cur = 0;
  for (int kt = 0; kt < 24; ++kt) {
    bf16x8 av[8], bvv[4];
#pragma unroll
    for (int m = 0; m < 8; ++m)
      av[m] = *(const bf16x8*)&lds[cur][g * 2048 + (wm2 * 128 + m * 16 + c15) * 8];
#pragma unroll
    for (int n = 0; n < 4; ++n)
      bvv[n] = *(const bf16x8*)&lds[cur][8192 + g * 2048 + (wn2 * 64 + n * 16 + c15) * 8];
#pragma unroll
    for (int m = 0; m < 8; ++m)
#pragma unroll
      for (int n = 0; n < 4; ++n)
        acc[m][n] = __builtin_amdgcn_mfma_f32_16x16x32_bf16(av[m], bvv[n], acc[m][n], 0, 0, 0);
    if (kt + 1 < 24) {
      swrite(cur ^ 1);               // write tile kt+1 (regs) to other buffer
      if (kt + 2 < 24) gload(kt + 2);  // issue loads for tile kt+2
    }
    __syncthreads();                 // reads of buf[cur] + writes of buf[cur^1] done
    cur ^= 1;
  }

  // epilogue: this wave's 64 cols = exactly one head of one of Q/K/V
  const int cwb = n0 + wn2 * 64;     // 64-aligned within one 768-mat
  const int mat = cwb / 768;
  const int cwm = cwb - mat * 768;
  const int hh = cwm >> 6;
  const float* bsel = (mat == 0) ? b0 : (mat == 1) ? b1 : b2;
  unsigned short* qk = (mat == 0) ? Qb : Kb;
#pragma unroll
  for (int n = 0; n < 4; ++n) {
    const int dd = n * 16 + c15;
    const float bval = bsel[hh * 64 + dd];
#pragma unroll
    for (int m = 0; m < 8; ++m) {
      const int r0 = m0 + wm2 * 128 + m * 16 + g * 4;
      const int bb = r0 >> 10;
      const int nn = r0 & 1023;
      if (mat < 2) {
        unsigned short* dst = qk + ((bb * 12 + hh) * 1024 + nn) * 64 + dd;
#pragma unroll
        for (int r = 0; r < 4; ++r) dst[r * 64] = f2bf(acc[m][n][r] + bval);
      } else {
        ushort4 w;
        w.x = f2bf(acc[m][n][0] + bval);
        w.y = f2bf(acc[m][n][1] + bval);
        w.z = f2bf(acc[m][n][2] + bval);
        w.w = f2bf(acc[m][n][3] + bval);
        *(ushort4*)&Vt[((bb * 12 + hh) * 64 + dd) * 1024 + nn] = w;
      }
    }
  }
}

// ---------------- output GEMM: 128x128, BK=32, 2D grid, 4 blocks/CU ----------------
__global__ __launch_bounds__(256, 4)
void gemm_out(const unsigned short* __restrict__ A, const unsigned short* __restrict__ Bt,
              const float* __restrict__ b0, float* __restrict__ Fo) {
  __shared__ __attribute__((aligned(16))) unsigned short lds[2][8192];
  const int t = threadIdx.x;
  const int lane = t & 63;
  const int wid = t >> 6;
  const int m0 = blockIdx.x * 128;
  const int n0 = blockIdx.y * 128;
  const int wm = (wid >> 1) * 64;
  const int wn = (wid & 1) * 64;
  const int srow = t & 127;
  const int sk8 = (t >> 7) * 8;

  const unsigned short* gA = A + (m0 + srow) * 768 + sk8;
  const unsigned short* gB = Bt + (n0 + srow) * 768 + sk8;

  const f32x4 Z4 = {0.f, 0.f, 0.f, 0.f};
  f32x4 acc[4][4];
#pragma unroll
  for (int m = 0; m < 4; ++m)
#pragma unroll
    for (int n = 0; n < 4; ++n) acc[m][n] = Z4;

  const int a_off = (lane >> 4) * 1024 + (wm + (lane & 15)) * 8;
  const int b_off = 4096 + (lane >> 4) * 1024 + (wn + (lane & 15)) * 8;

  auto stage = [&](int buf, int kt) {
    unsigned short* dA = &lds[buf][0] + wid * 512;
    unsigned short* dB = &lds[buf][4096] + wid * 512;
    const unsigned short* sA = gA + kt * 32;
    const unsigned short* sB = gB + kt * 32;
    lds_load16(dA, sA);
    lds_load16(dA + 2048, sA + 16);
    lds_load16(dB, sB);
    lds_load16(dB + 2048, sB + 16);
  };

  stage(0, 0);
  int cur = 0;
  for (int kt = 0; kt < 24; ++kt) {
    __syncthreads();
    if (kt + 1 < 24) stage(cur ^ 1, kt + 1);
    bf16x8 av[4], bvv[4];
#pragma unroll
    for (int m = 0; m < 4; ++m) av[m] = *(const bf16x8*)&lds[cur][a_off + m * 128];
#pragma unroll
    for (int n = 0; n < 4; ++n) bvv[n] = *(const bf16x8*)&lds[cur][b_off + n * 128];
#pragma unroll
    for (int m = 0; m < 4; ++m)
#pragma unroll
      for (int n = 0; n < 4; ++n)
        acc[m][n] = __builtin_amdgcn_mfma_f32_16x16x32_bf16(av[m], bvv[n], acc[m][n], 0, 0, 0);
    cur ^= 1;
  }

  const int g = lane >> 4;
  const int c15 = lane & 15;
#pragma unroll
  for (int n = 0; n < 4; ++n) {
    const int col = n0 + wn + n * 16 + c15;
    const float bval = b0[col];
#pragma unroll
    for (int m = 0; m < 4; ++m) {
      const int r0 = m0 + wm + m * 16 + g * 4;
#pragma unroll
      for (int r = 0; r < 4; ++r) Fo[(r0 + r) * 768 + col] = acc[m][n][r] + bval;
    }
  }
}

// ---------------- fused attention, swapped-QK^T 32x32 (m214 structure) ----------------
__global__ __launch_bounds__(256, 4)
void attn_fused(const unsigned short* __restrict__ Qb, const unsigned short* __restrict__ Kb,
                const unsigned short* __restrict__ Vt, const uint8_t* __restrict__ E8L,
                const float* __restrict__ emb, unsigned short* __restrict__ AO) {
  __shared__ __attribute__((aligned(16))) unsigned short Ks[2][4096];  // [krow64][d64] swz
  __shared__ __attribute__((aligned(16))) unsigned short Vs[2][4096];  // [d64][k64] swz
  __shared__ float ttab[33];
  __shared__ float red[4][32];

  const int t = threadIdx.x;
  const int lane = t & 63;
  const int wid = t >> 6;
  const int l31 = lane & 31;
  const int hl = lane >> 5;

  const int id = blockIdx.x;
  const int sw = (id & 7) * 96 + (id >> 3);
  const int b = sw / 96;
  const int rem = sw - b * 96;
  const int h = rem >> 3;
  const int qb = rem & 7;
  const int bh = b * 12 + h;
  const int qw = qb * 4 + wid;
  const int q0 = qw * 32;

  if (t < 33) ttab[t] = (t < 32) ? emb[t * 12 + h] * 1.44269504f : -1e30f;

  bf16x8 qf[4];
  {
    const unsigned short* qp = Qb + ((size_t)bh * 1024 + q0 + l31) * 64 + hl * 8;
#pragma unroll
    for (int dc = 0; dc < 4; ++dc) qf[dc] = *(const bf16x8*)(qp + dc * 16);
  }

  auto stageKV = [&](int buf, int kt) {
#pragma unroll
    for (int i = 0; i < 2; ++i) {
      const int c = i * 256 + t;
      const int row = c >> 3, c16 = c & 7;
      const int sc = (c16 ^ (row & 7)) * 8;
      lds_load16(&Ks[buf][i * 2048 + wid * 512],
                 Kb + ((size_t)bh * 1024 + kt * 64 + row) * 64 + sc);
      lds_load16(&Vs[buf][i * 2048 + wid * 512],
                 Vt + ((size_t)bh * 64 + row) * 1024 + kt * 64 + sc);
    }
  };

  const uint8_t* ebase = E8L + (((size_t)(b * 32 + qw)) * 16 * 64 + lane) * 32;

  stageKV(0, 0);
  uint4 e0 = *(const uint4*)(ebase);
  uint4 e1 = *(const uint4*)(ebase + 16);

  const f32x16 Z16 = {0.f};
  f32x16 oacc0 = Z16, oacc1 = Z16;
  float m = -3.0e38f, lsum = 0.f;
  int cur = 0;

  for (int kt = 0; kt < 16; ++kt) {
    __syncthreads();
    if (kt + 1 < 16) stageKV(cur ^ 1, kt + 1);
    uint4 en0 = e0, en1 = e1;  // defined on last iter
    if (kt + 1 < 16) {
      en0 = *(const uint4*)(ebase + (kt + 1) * 2048);
      en1 = *(const uint4*)(ebase + (kt + 1) * 2048 + 16);
    }

    f32x16 s0 = Z16, s1 = Z16;
    __builtin_amdgcn_s_setprio(1);
#pragma unroll
    for (int dc = 0; dc < 4; ++dc) {
      const int gch = (dc * 2 + hl);
      const bf16x8 a0 = *(const bf16x8*)((const char*)Ks[cur] +
                         l31 * 128 + ((gch ^ (l31 & 7)) << 4));
      const bf16x8 a1 = *(const bf16x8*)((const char*)Ks[cur] +
                         (32 + l31) * 128 + ((gch ^ ((32 + l31) & 7)) << 4));
      s0 = __builtin_amdgcn_mfma_f32_32x32x16_bf16(a0, qf[dc], s0, 0, 0, 0);
      s1 = __builtin_amdgcn_mfma_f32_32x32x16_bf16(a1, qf[dc], s1, 0, 0, 0);
    }
    __builtin_amdgcn_s_setprio(0);

    const uint32_t ed[8] = {e0.x, e0.y, e0.z, e0.w, e1.x, e1.y, e1.z, e1.w};
    float w0[16], w1[16];
#pragma unroll
    for (int r = 0; r < 16; ++r) {
      const uint32_t d0 = ed[r >> 2], d1 = ed[4 + (r >> 2)];
      const int sh = (r & 3) * 8;
      w0[r] = fmaf(s0[r], 0.18033688f, ttab[(d0 >> sh) & 0xffu]);
      w1[r] = fmaf(s1[r], 0.18033688f, ttab[(d1 >> sh) & 0xffu]);
    }

    float rm = fmaxf(w0[0], w1[0]);
#pragma unroll
    for (int r = 1; r < 16; ++r) rm = fmaxf(rm, fmaxf(w0[r], w1[r]));
    rm = fmaxf(rm, __shfl_xor(rm, 32, 64));

    if (__any(rm > m + 11.5415603f)) {
      const float mn = fmaxf(m, rm);
      const float scl = exp2f(m - mn);
      m = mn;
      lsum *= scl;
#pragma unroll
      for (int r = 0; r < 16; ++r) { oacc0[r] *= scl; oacc1[r] *= scl; }
    }

    float rs0 = 0.f, rs1 = 0.f, rs2 = 0.f, rs3 = 0.f;
#pragma unroll
    for (int r = 0; r < 16; ++r) {
      w0[r] = exp2f(w0[r] - m);
      w1[r] = exp2f(w1[r] - m);
    }
#pragma unroll
    for (int r = 0; r < 4; ++r) {
      rs0 += w0[r];  rs1 += w0[4 + r];
      rs2 += w0[8 + r]; rs3 += w0[12 + r];
      rs0 += w1[r];  rs1 += w1[4 + r];
      rs2 += w1[8 + r]; rs3 += w1[12 + r];
    }
    float rs = (rs0 + rs1) + (rs2 + rs3);
    rs += __shfl_xor(rs, 32, 64);
    lsum += rs;

    uint32_t wd0[8], wd1[8];
#pragma unroll
    for (int j = 0; j < 8; ++j) {
      asm("v_cvt_pk_bf16_f32 %0, %1, %2" : "=v"(wd0[j]) : "v"(w0[2 * j]), "v"(w0[2 * j + 1]));
      asm("v_cvt_pk_bf16_f32 %0, %1, %2" : "=v"(wd1[j]) : "v"(w1[2 * j]), "v"(w1[2 * j + 1]));
    }
#pragma unroll
    for (int cc = 0; cc < 2; ++cc) {
      asm volatile("v_permlane32_swap_b32 %0, %1" : "+v"(wd0[4 * cc]), "+v"(wd0[4 * cc + 2]));
      asm volatile("v_permlane32_swap_b32 %0, %1" : "+v"(wd0[4 * cc + 1]), "+v"(wd0[4 * cc + 3]));
      asm volatile("v_permlane32_swap_b32 %0, %1" : "+v"(wd1[4 * cc]), "+v"(wd1[4 * cc + 2]));
      asm volatile("v_permlane32_swap_b32 %0, %1" : "+v"(wd1[4 * cc + 1]), "+v"(wd1[4 * cc + 3]));
    }

    __builtin_amdgcn_s_setprio(1);
#pragma unroll
    for (int kb = 0; kb < 4; ++kb) {
      union { uint32_t u[4]; bf16x8 v; } fu;
      const uint32_t* wds = (kb < 2) ? wd0 : wd1;
      const int cc = kb & 1;
      fu.u[0] = wds[4 * cc];     fu.u[1] = wds[4 * cc + 1];
      fu.u[2] = wds[4 * cc + 2]; fu.u[3] = wds[4 * cc + 3];
      const int gch = kb * 2 + hl;
      const bf16x8 v0 = *(const bf16x8*)((const char*)Vs[cur] +
                         l31 * 128 + ((gch ^ (l31 & 7)) << 4));
      const bf16x8 v1 = *(const bf16x8*)((const char*)Vs[cur] +
                         (32 + l31) * 128 + ((gch ^ ((32 + l31) & 7)) << 4));
      oacc0 = __builtin_amdgcn_mfma_f32_32x32x16_bf16(fu.v, v0, oacc0, 0, 0, 0);
      oacc1 = __builtin_amdgcn_mfma_f32_32x32x16_bf16(fu.v, v1, oacc1, 0, 0, 0);
    }
    __builtin_amdgcn_s_setprio(0);

    e0 = en0; e1 = en1;
    cur ^= 1;
  }

  red[wid][l31] = 1.0f / lsum;
  __syncthreads();
  unsigned short* aob = AO + ((size_t)b * 1024 + q0) * 768 + h * 64;
#pragma unroll
  for (int j = 0; j < 4; ++j) {
    const f32x4 lv = *(const f32x4*)&red[wid][8 * j + 4 * hl];
#pragma unroll
    for (int rr = 0; rr < 4; ++rr) {
      const int rowq = rr + 8 * j + 4 * hl;
      const int reg = 4 * j + rr;
      aob[rowq * 768 + l31]      = f2bf(oacc0[reg] * lv[rr]);
      aob[rowq * 768 + 32 + l31] = f2bf(oacc1[reg] * lv[rr]);
    }
  }
}

// ---------------- launch ----------------

extern "C" void kernel_launch(void* const* d_in, const int* in_sizes, int n_in,
                              void* d_out, int out_size, void* d_ws, size_t ws_size,
                              hipStream_t stream) {
  (void)in_sizes; (void)n_in; (void)out_size; (void)ws_size;
  const float* x = (const float*)d_in[0];
  const int* E = (const int*)d_in[1];
  const int* Mm = (const int*)d_in[2];
  const float* Wq = (const float*)d_in[3];
  const float* bq = (const float*)d_in[4];
  const float* Wk = (const float*)d_in[5];
  const float* bk = (const float*)d_in[6];
  const float* Wv = (const float*)d_in[7];
  const float* bv = (const float*)d_in[8];
  const float* Wo = (const float*)d_in[9];
  const float* bo = (const float*)d_in[10];
  const float* emb = (const float*)d_in[11];
  float* out = (float*)d_out;

  char* w = (char*)d_ws;
  unsigned short* x16 = (unsigned short*)w;  // reused as AO after gemm256_qkv
  unsigned short* AO = x16;
  w += (size_t)8192 * 768 * 2;
  unsigned short* wtqkv = (unsigned short*)w; w += (size_t)2304 * 768 * 2;
  unsigned short* wot = (unsigned short*)w;   w += (size_t)768 * 768 * 2;
  unsigned short* Qb = (unsigned short*)w;    w += (size_t)8 * 12 * 1024 * 64 * 2;
  unsigned short* Kb = (unsigned short*)w;    w += (size_t)8 * 12 * 1024 * 64 * 2;
  unsigned short* Vt = (unsigned short*)w;    w += (size_t)8 * 12 * 64 * 1024 * 2;
  uint8_t* E8L = (uint8_t*)w;                 w += (size_t)8 * 1024 * 1024;

  conv_x_k<<<6144, 256, 0, stream>>>(x, x16);
  conv_E_k<<<8192, 256, 0, stream>>>(E, Mm, E8L);
  transp_w_k<<<dim3(12, 12, 4), 256, 0, stream>>>(Wq, Wk, Wv, Wo, wtqkv, wot);
  gemm256_qkv<<<dim3(32, 9), 512, 0, stream>>>(x16, wtqkv, bq, bk, bv, Qb, Kb, Vt);
  attn_fused<<<768, 256, 0, stream>>>(Qb, Kb, Vt, E8L, emb, AO);
  gemm_out<<<dim3(64, 6), 256, 0, stream>>>(AO, wot, bo, out);
}

// Round 13
// 177.208 us; speedup vs baseline: 2.6740x; 1.0306x over previous
//
#include <hip/hip_runtime.h>
#include <stdint.h>

#define DEV __device__ __forceinline__

typedef __attribute__((ext_vector_type(8))) short bf16x8;
typedef __attribute__((ext_vector_type(4))) float f32x4;
typedef __attribute__((ext_vector_type(16))) float f32x16;

DEV unsigned short f2bf(float f) {
  union { float f; uint32_t u; } v; v.f = f;
  uint32_t r = v.u + 0x7fffu + ((v.u >> 16) & 1u);
  return (unsigned short)(r >> 16);
}

DEV void lds_load16(void* dst, const void* src) {
  __builtin_amdgcn_global_load_lds(
      (const __attribute__((address_space(1))) unsigned int*)src,
      (__attribute__((address_space(3))) unsigned int*)dst, 16, 0, 0);
}

// ---------------- prep kernels ----------------

__global__ void conv_x_k(const float* __restrict__ x, unsigned short* __restrict__ o) {
  const int i = blockIdx.x * 256 + threadIdx.x;  // 1572864 float4s
  const float4 v = ((const float4*)x)[i];
  ushort4 u;
  u.x = f2bf(v.x); u.y = f2bf(v.y); u.z = f2bf(v.z); u.w = f2bf(v.w);
  ((ushort4*)o)[i] = u;
}

// E (int32) -> lane-ordered masked-index records.
__global__ void conv_E_k(const int* __restrict__ E, const int* __restrict__ Mm,
                         uint8_t* __restrict__ E8L) {
  const int tid = blockIdx.x * 256 + threadIdx.x;  // 2097152
  const int k4 = tid & 255;
  const int q = (tid >> 8) & 1023;
  const int b = tid >> 18;
  const uint4 e = ((const uint4*)E)[tid];
  const int mq = Mm[b * 1024 + q];
  const int4 mk = *(const int4*)&Mm[b * 1024 + k4 * 4];
  uint32_t r;
  {
    const uint32_t b0 = (mq && mk.x) ? (e.x & 31u) : 32u;
    const uint32_t b1 = (mq && mk.y) ? (e.y & 31u) : 32u;
    const uint32_t b2 = (mq && mk.z) ? (e.z & 31u) : 32u;
    const uint32_t b3 = (mq && mk.w) ? (e.w & 31u) : 32u;
    r = b0 | (b1 << 8) | (b2 << 16) | (b3 << 24);
  }
  const int kt = k4 >> 4;
  const int k4t = k4 & 15;
  const int h = k4t & 1, c = (k4t >> 1) & 3, a = k4t >> 3;
  const int lane = (h << 5) | (q & 31);
  const int qw = q >> 5;
  const int j = a * 4 + c;
  const size_t rec = ((((size_t)b * 32 + qw) * 16 + kt) * 64 + lane) * 32 + j * 4;
  *(uint32_t*)(E8L + rec) = r;
}

// Wt[c][k] = W[k][c], bf16 pack. grid (12,12,4)
__global__ void transp_w_k(const float* __restrict__ Wq, const float* __restrict__ Wk,
                           const float* __restrict__ Wv, const float* __restrict__ Wo,
                           unsigned short* __restrict__ wtqkv, unsigned short* __restrict__ wot) {
  __shared__ float tile[64][65];
  const int z = blockIdx.z;
  const float* W = (z == 0) ? Wq : (z == 1) ? Wk : (z == 2) ? Wv : Wo;
  unsigned short* D = (z < 3) ? wtqkv + (size_t)z * 768 * 768 : wot;
  const int k0 = blockIdx.x * 64;
  const int c0 = blockIdx.y * 64;
  const int t = threadIdx.x;
#pragma unroll
  for (int i = 0; i < 4; ++i) {
    const int idx = i * 256 + t;
    const int r = idx >> 4;
    const int cq = (idx & 15) * 4;
    const float4 v = *(const float4*)&W[(k0 + r) * 768 + c0 + cq];
    tile[r][cq] = v.x; tile[r][cq + 1] = v.y; tile[r][cq + 2] = v.z; tile[r][cq + 3] = v.w;
  }
  __syncthreads();
#pragma unroll
  for (int i = 0; i < 4; ++i) {
    const int idx = i * 256 + t;
    const int c = idx >> 4;
    const int kq = (idx & 15) * 4;
    ushort4 u;
    u.x = f2bf(tile[kq][c]);     u.y = f2bf(tile[kq + 1][c]);
    u.z = f2bf(tile[kq + 2][c]); u.w = f2bf(tile[kq + 3][c]);
    *(ushort4*)&D[(c0 + c) * 768 + k0 + kq] = u;
  }
}

// ---------------- GEMM: C = A(M,768) @ Bt^T + bias ----------------
// r3-proven structure: 128x128 tile, BK=32, double-buffer, global_load_lds,
// natural 2D grid. Single knob vs r3: launch_bounds (256,3) -> 3 blocks/CU
// (96 KB LDS, VGPR cap 170 > 68: no spill).
// MODE 0: Ncols=2304 (Q|K|V) -> scatter to Qb,Kb (B,h,N,d) and Vt (B,h,d,N), bf16.
// MODE 1: Ncols=768 -> Fo f32 (M,768) + bias.
template <int MODE>
__global__ __launch_bounds__(256, 3)
void gemm_bt(const unsigned short* __restrict__ A, const unsigned short* __restrict__ Bt,
             const float* __restrict__ b0, const float* __restrict__ b1, const float* __restrict__ b2,
             unsigned short* __restrict__ Qb, unsigned short* __restrict__ Kb,
             unsigned short* __restrict__ Vt, float* __restrict__ Fo) {
  __shared__ __attribute__((aligned(16))) unsigned short lds[2][8192];  // [buf][A 4096 | B 4096]
  const int t = threadIdx.x;
  const int lane = t & 63;
  const int wid = t >> 6;
  const int m0 = blockIdx.x * 128;
  const int n0 = blockIdx.y * 128;
  const int wm = (wid >> 1) * 64;
  const int wn = (wid & 1) * 64;
  const int srow = t & 127;
  const int sk8 = (t >> 7) * 8;

  const unsigned short* gA = A + (m0 + srow) * 768 + sk8;
  const unsigned short* gB = Bt + (n0 + srow) * 768 + sk8;

  const f32x4 Z4 = {0.f, 0.f, 0.f, 0.f};
  f32x4 acc[4][4];
#pragma unroll
  for (int m = 0; m < 4; ++m)
#pragma unroll
    for (int n = 0; n < 4; ++n) acc[m][n] = Z4;

  const int a_off = (lane >> 4) * 1024 + (wm + (lane & 15)) * 8;
  const int b_off = 4096 + (lane >> 4) * 1024 + (wn + (lane & 15)) * 8;

  auto stage = [&](int buf, int kt) {
    unsigned short* dA = &lds[buf][0] + wid * 512;
    unsigned short* dB = &lds[buf][4096] + wid * 512;
    const unsigned short* sA = gA + kt * 32;
    const unsigned short* sB = gB + kt * 32;
    lds_load16(dA, sA);
    lds_load16(dA + 2048, sA + 16);
    lds_load16(dB, sB);
    lds_load16(dB + 2048, sB + 16);
  };

  stage(0, 0);
  int cur = 0;
  for (int kt = 0; kt < 24; ++kt) {
    __syncthreads();
    if (kt + 1 < 24) stage(cur ^ 1, kt + 1);
    bf16x8 av[4], bvv[4];
#pragma unroll
    for (int m = 0; m < 4; ++m) av[m] = *(const bf16x8*)&lds[cur][a_off + m * 128];
#pragma unroll
    for (int n = 0; n < 4; ++n) bvv[n] = *(const bf16x8*)&lds[cur][b_off + n * 128];
#pragma unroll
    for (int m = 0; m < 4; ++m)
#pragma unroll
      for (int n = 0; n < 4; ++n)
        acc[m][n] = __builtin_amdgcn_mfma_f32_16x16x32_bf16(av[m], bvv[n], acc[m][n], 0, 0, 0);
    cur ^= 1;
  }

  const int g = lane >> 4;
  const int c15 = lane & 15;
  if (MODE == 1) {
#pragma unroll
    for (int n = 0; n < 4; ++n) {
      const int col = n0 + wn + n * 16 + c15;
      const float bval = b0[col];
#pragma unroll
      for (int m = 0; m < 4; ++m) {
        const int r0 = m0 + wm + m * 16 + g * 4;
#pragma unroll
        for (int r = 0; r < 4; ++r) Fo[(r0 + r) * 768 + col] = acc[m][n][r] + bval;
      }
    }
  } else {
    const int mat = blockIdx.y / 6;
    const float* bsel = (mat == 0) ? b0 : (mat == 1) ? b1 : b2;
    unsigned short* qk = (mat == 0) ? Qb : Kb;
#pragma unroll
    for (int n = 0; n < 4; ++n) {
      const int cw = (blockIdx.y % 6) * 128 + wn + n * 16 + c15;  // col within matrix
      const int hh = cw >> 6, dd = cw & 63;
      const float bval = bsel[cw];
#pragma unroll
      for (int m = 0; m < 4; ++m) {
        const int r0 = m0 + wm + m * 16 + g * 4;
        const int bb = r0 >> 10;
        const int nn = r0 & 1023;
        if (mat < 2) {
          unsigned short* dst = qk + ((bb * 12 + hh) * 1024 + nn) * 64 + dd;
#pragma unroll
          for (int r = 0; r < 4; ++r) dst[r * 64] = f2bf(acc[m][n][r] + bval);
        } else {
          ushort4 w;
          w.x = f2bf(acc[m][n][0] + bval);
          w.y = f2bf(acc[m][n][1] + bval);
          w.z = f2bf(acc[m][n][2] + bval);
          w.w = f2bf(acc[m][n][3] + bval);
          *(ushort4*)&Vt[((bb * 12 + hh) * 64 + dd) * 1024 + nn] = w;
        }
      }
    }
  }
}

// ---------------- fused attention, swapped-QK^T 32x32 (m214 structure) ----------------
__global__ __launch_bounds__(256, 4)
void attn_fused(const unsigned short* __restrict__ Qb, const unsigned short* __restrict__ Kb,
                const unsigned short* __restrict__ Vt, const uint8_t* __restrict__ E8L,
                const float* __restrict__ emb, unsigned short* __restrict__ AO) {
  __shared__ __attribute__((aligned(16))) unsigned short Ks[2][4096];  // [krow64][d64] swz
  __shared__ __attribute__((aligned(16))) unsigned short Vs[2][4096];  // [d64][k64] swz
  __shared__ float ttab[33];
  __shared__ float red[4][32];

  const int t = threadIdx.x;
  const int lane = t & 63;
  const int wid = t >> 6;
  const int l31 = lane & 31;
  const int hl = lane >> 5;

  const int id = blockIdx.x;
  const int sw = (id & 7) * 96 + (id >> 3);
  const int b = sw / 96;
  const int rem = sw - b * 96;
  const int h = rem >> 3;
  const int qb = rem & 7;
  const int bh = b * 12 + h;
  const int qw = qb * 4 + wid;
  const int q0 = qw * 32;

  if (t < 33) ttab[t] = (t < 32) ? emb[t * 12 + h] * 1.44269504f : -1e30f;

  bf16x8 qf[4];
  {
    const unsigned short* qp = Qb + ((size_t)bh * 1024 + q0 + l31) * 64 + hl * 8;
#pragma unroll
    for (int dc = 0; dc < 4; ++dc) qf[dc] = *(const bf16x8*)(qp + dc * 16);
  }

  auto stageKV = [&](int buf, int kt) {
#pragma unroll
    for (int i = 0; i < 2; ++i) {
      const int c = i * 256 + t;
      const int row = c >> 3, c16 = c & 7;
      const int sc = (c16 ^ (row & 7)) * 8;
      lds_load16(&Ks[buf][i * 2048 + wid * 512],
                 Kb + ((size_t)bh * 1024 + kt * 64 + row) * 64 + sc);
      lds_load16(&Vs[buf][i * 2048 + wid * 512],
                 Vt + ((size_t)bh * 64 + row) * 1024 + kt * 64 + sc);
    }
  };

  const uint8_t* ebase = E8L + (((size_t)(b * 32 + qw)) * 16 * 64 + lane) * 32;

  stageKV(0, 0);
  uint4 e0 = *(const uint4*)(ebase);
  uint4 e1 = *(const uint4*)(ebase + 16);

  const f32x16 Z16 = {0.f};
  f32x16 oacc0 = Z16, oacc1 = Z16;
  float m = -3.0e38f, lsum = 0.f;
  int cur = 0;

  for (int kt = 0; kt < 16; ++kt) {
    __syncthreads();
    if (kt + 1 < 16) stageKV(cur ^ 1, kt + 1);
    uint4 en0 = e0, en1 = e1;  // defined on last iter
    if (kt + 1 < 16) {
      en0 = *(const uint4*)(ebase + (kt + 1) * 2048);
      en1 = *(const uint4*)(ebase + (kt + 1) * 2048 + 16);
    }

    f32x16 s0 = Z16, s1 = Z16;
    __builtin_amdgcn_s_setprio(1);
#pragma unroll
    for (int dc = 0; dc < 4; ++dc) {
      const int gch = (dc * 2 + hl);
      const bf16x8 a0 = *(const bf16x8*)((const char*)Ks[cur] +
                         l31 * 128 + ((gch ^ (l31 & 7)) << 4));
      const bf16x8 a1 = *(const bf16x8*)((const char*)Ks[cur] +
                         (32 + l31) * 128 + ((gch ^ ((32 + l31) & 7)) << 4));
      s0 = __builtin_amdgcn_mfma_f32_32x32x16_bf16(a0, qf[dc], s0, 0, 0, 0);
      s1 = __builtin_amdgcn_mfma_f32_32x32x16_bf16(a1, qf[dc], s1, 0, 0, 0);
    }
    __builtin_amdgcn_s_setprio(0);

    const uint32_t ed[8] = {e0.x, e0.y, e0.z, e0.w, e1.x, e1.y, e1.z, e1.w};
    float w0[16], w1[16];
#pragma unroll
    for (int r = 0; r < 16; ++r) {
      const uint32_t d0 = ed[r >> 2], d1 = ed[4 + (r >> 2)];
      const int sh = (r & 3) * 8;
      w0[r] = fmaf(s0[r], 0.18033688f, ttab[(d0 >> sh) & 0xffu]);
      w1[r] = fmaf(s1[r], 0.18033688f, ttab[(d1 >> sh) & 0xffu]);
    }

    float rm = fmaxf(w0[0], w1[0]);
#pragma unroll
    for (int r = 1; r < 16; ++r) rm = fmaxf(rm, fmaxf(w0[r], w1[r]));
    rm = fmaxf(rm, __shfl_xor(rm, 32, 64));

    if (__any(rm > m + 11.5415603f)) {
      const float mn = fmaxf(m, rm);
      const float scl = exp2f(m - mn);
      m = mn;
      lsum *= scl;
#pragma unroll
      for (int r = 0; r < 16; ++r) { oacc0[r] *= scl; oacc1[r] *= scl; }
    }

    float rs0 = 0.f, rs1 = 0.f, rs2 = 0.f, rs3 = 0.f;
#pragma unroll
    for (int r = 0; r < 16; ++r) {
      w0[r] = exp2f(w0[r] - m);
      w1[r] = exp2f(w1[r] - m);
    }
#pragma unroll
    for (int r = 0; r < 4; ++r) {
      rs0 += w0[r];  rs1 += w0[4 + r];
      rs2 += w0[8 + r]; rs3 += w0[12 + r];
      rs0 += w1[r];  rs1 += w1[4 + r];
      rs2 += w1[8 + r]; rs3 += w1[12 + r];
    }
    float rs = (rs0 + rs1) + (rs2 + rs3);
    rs += __shfl_xor(rs, 32, 64);
    lsum += rs;

    uint32_t wd0[8], wd1[8];
#pragma unroll
    for (int j = 0; j < 8; ++j) {
      asm("v_cvt_pk_bf16_f32 %0, %1, %2" : "=v"(wd0[j]) : "v"(w0[2 * j]), "v"(w0[2 * j + 1]));
      asm("v_cvt_pk_bf16_f32 %0, %1, %2" : "=v"(wd1[j]) : "v"(w1[2 * j]), "v"(w1[2 * j + 1]));
    }
#pragma unroll
    for (int cc = 0; cc < 2; ++cc) {
      asm volatile("v_permlane32_swap_b32 %0, %1" : "+v"(wd0[4 * cc]), "+v"(wd0[4 * cc + 2]));
      asm volatile("v_permlane32_swap_b32 %0, %1" : "+v"(wd0[4 * cc + 1]), "+v"(wd0[4 * cc + 3]));
      asm volatile("v_permlane32_swap_b32 %0, %1" : "+v"(wd1[4 * cc]), "+v"(wd1[4 * cc + 2]));
      asm volatile("v_permlane32_swap_b32 %0, %1" : "+v"(wd1[4 * cc + 1]), "+v"(wd1[4 * cc + 3]));
    }

    __builtin_amdgcn_s_setprio(1);
#pragma unroll
    for (int kb = 0; kb < 4; ++kb) {
      union { uint32_t u[4]; bf16x8 v; } fu;
      const uint32_t* wds = (kb < 2) ? wd0 : wd1;
      const int cc = kb & 1;
      fu.u[0] = wds[4 * cc];     fu.u[1] = wds[4 * cc + 1];
      fu.u[2] = wds[4 * cc + 2]; fu.u[3] = wds[4 * cc + 3];
      const int gch = kb * 2 + hl;
      const bf16x8 v0 = *(const bf16x8*)((const char*)Vs[cur] +
                         l31 * 128 + ((gch ^ (l31 & 7)) << 4));
      const bf16x8 v1 = *(const bf16x8*)((const char*)Vs[cur] +
                         (32 + l31) * 128 + ((gch ^ ((32 + l31) & 7)) << 4));
      oacc0 = __builtin_amdgcn_mfma_f32_32x32x16_bf16(fu.v, v0, oacc0, 0, 0, 0);
      oacc1 = __builtin_amdgcn_mfma_f32_32x32x16_bf16(fu.v, v1, oacc1, 0, 0, 0);
    }
    __builtin_amdgcn_s_setprio(0);

    e0 = en0; e1 = en1;
    cur ^= 1;
  }

  red[wid][l31] = 1.0f / lsum;
  __syncthreads();
  unsigned short* aob = AO + ((size_t)b * 1024 + q0) * 768 + h * 64;
#pragma unroll
  for (int j = 0; j < 4; ++j) {
    const f32x4 lv = *(const f32x4*)&red[wid][8 * j + 4 * hl];
#pragma unroll
    for (int rr = 0; rr < 4; ++rr) {
      const int rowq = rr + 8 * j + 4 * hl;
      const int reg = 4 * j + rr;
      aob[rowq * 768 + l31]      = f2bf(oacc0[reg] * lv[rr]);
      aob[rowq * 768 + 32 + l31] = f2bf(oacc1[reg] * lv[rr]);
    }
  }
}

// ---------------- launch ----------------

extern "C" void kernel_launch(void* const* d_in, const int* in_sizes, int n_in,
                              void* d_out, int out_size, void* d_ws, size_t ws_size,
                              hipStream_t stream) {
  (void)in_sizes; (void)n_in; (void)out_size; (void)ws_size;
  const float* x = (const float*)d_in[0];
  const int* E = (const int*)d_in[1];
  const int* Mm = (const int*)d_in[2];
  const float* Wq = (const float*)d_in[3];
  const float* bq = (const float*)d_in[4];
  const float* Wk = (const float*)d_in[5];
  const float* bk = (const float*)d_in[6];
  const float* Wv = (const float*)d_in[7];
  const float* bv = (const float*)d_in[8];
  const float* Wo = (const float*)d_in[9];
  const float* bo = (const float*)d_in[10];
  const float* emb = (const float*)d_in[11];
  float* out = (float*)d_out;

  char* w = (char*)d_ws;
  unsigned short* x16 = (unsigned short*)w;  // reused as AO after gemm_bt<0>
  unsigned short* AO = x16;
  w += (size_t)8192 * 768 * 2;
  unsigned short* wtqkv = (unsigned short*)w; w += (size_t)2304 * 768 * 2;
  unsigned short* wot = (unsigned short*)w;   w += (size_t)768 * 768 * 2;
  unsigned short* Qb = (unsigned short*)w;    w += (size_t)8 * 12 * 1024 * 64 * 2;
  unsigned short* Kb = (unsigned short*)w;    w += (size_t)8 * 12 * 1024 * 64 * 2;
  unsigned short* Vt = (unsigned short*)w;    w += (size_t)8 * 12 * 64 * 1024 * 2;
  uint8_t* E8L = (uint8_t*)w;                 w += (size_t)8 * 1024 * 1024;

  conv_x_k<<<6144, 256, 0, stream>>>(x, x16);
  conv_E_k<<<8192, 256, 0, stream>>>(E, Mm, E8L);
  transp_w_k<<<dim3(12, 12, 4), 256, 0, stream>>>(Wq, Wk, Wv, Wo, wtqkv, wot);
  gemm_bt<0><<<dim3(64, 18), 256, 0, stream>>>(x16, wtqkv, bq, bk, bv, Qb, Kb, Vt, nullptr);
  attn_fused<<<768, 256, 0, stream>>>(Qb, Kb, Vt, E8L, emb, AO);
  gemm_bt<1><<<dim3(64, 6), 256, 0, stream>>>(AO, wot, bo, nullptr, nullptr,
                                              nullptr, nullptr, nullptr, out);
}